// Round 4
// baseline (2853.257 us; speedup 1.0000x reference)
//
#include <hip/hip_runtime.h>
#include <math.h>

// ---------------------------------------------------------------------------
// GraphBased_selfAttnLayer — fp32, workspace-adaptive t-striped pipeline.
//
//   1. q,k,v = x@W^T + b            (one fused kernel, 384 blocks)
//   2. scale = 1/(||q||_F ||k||_F)  (two-stage deterministic reduction)
//   3. for each t-stripe [s0, s0+Wc):
//        a. S = scale*(Q @ K_stripe^T), cols s0-1 .. s0+Wc (halo, 0 at edges)
//        b. attn (+)= conv3x3(S) @ V_stripe   (fused, SAME zero-pad via S)
//   4. h = x + LN1(attn); l2 = LN2(h)    (attn,h in d_out, in-place)
//   5. z = l2 @ m1w^T ; BN column stats ; out = h + relu(z*a+b) @ m2w^T
//
// ws floats: [Q 2M][K 2M][V 2M][RED 512][SC 16][BNA 128][BNB 128][stripe ...]
// L2 aliases Q, Z aliases K (both dead after the stripe loop).
// ---------------------------------------------------------------------------

#define N_ 8192
#define D_ 256
#define H_ 128
#define EPSF 1e-5f
#define NF 2097152UL   // N_*D_

static const size_t OFF_RED    = 3UL * NF;            // 6291456
static const size_t OFF_SC     = OFF_RED + 512;
static const size_t OFF_BNA    = OFF_SC + 16;
static const size_t OFF_BNB    = OFF_BNA + 128;
static const size_t OFF_STRIPE = 6292480UL;           // rounded up

// ---------------------------------------------------------------------------
// Fused q/k/v GEMM: blockIdx.y in 0..5 -> (sel = y>>1 chooses wq/wk/wv,
// y&1 chooses column half). C = x@W^T + b, 128x128 tile, 8x8 microtile.
// ---------------------------------------------------------------------------
__global__ void __launch_bounds__(256, 2)
qkv_nt(const float* __restrict__ x,
       const float* __restrict__ wq, const float* __restrict__ bq,
       const float* __restrict__ wk, const float* __restrict__ bk,
       const float* __restrict__ wv, const float* __restrict__ bv,
       float* __restrict__ QKV)
{
    __shared__ float XsT[32][132];
    __shared__ float WsT[32][132];
    const int sel = blockIdx.y >> 1;
    const float* W = (sel == 0) ? wq : ((sel == 1) ? wk : wv);
    const float* B = (sel == 0) ? bq : ((sel == 1) ? bk : bv);
    float* C = QKV + (size_t)sel * NF;
    const int tid = threadIdx.x;
    const int i0 = blockIdx.x * 128;
    const int j0 = (blockIdx.y & 1) * 128;
    const int tr = tid >> 4, tc = tid & 15;
    float acc[8][8] = {};

    for (int k0 = 0; k0 < D_; k0 += 32) {
        __syncthreads();
#pragma unroll
        for (int p = 0; p < 16; ++p) {
            int idx = tid + p * 256;
            int r = idx >> 5, c = idx & 31;
            XsT[c][r] = x[(size_t)(i0 + r) * D_ + (k0 + c)];
            WsT[c][r] = W[(size_t)(j0 + r) * D_ + (k0 + c)];
        }
        __syncthreads();
#pragma unroll
        for (int kk = 0; kk < 32; ++kk) {
            float a[8], b[8];
            *(float4*)&a[0] = *(const float4*)&XsT[kk][tr * 8];
            *(float4*)&a[4] = *(const float4*)&XsT[kk][tr * 8 + 4];
            *(float4*)&b[0] = *(const float4*)&WsT[kk][tc * 8];
            *(float4*)&b[4] = *(const float4*)&WsT[kk][tc * 8 + 4];
#pragma unroll
            for (int u = 0; u < 8; ++u)
#pragma unroll
                for (int w2 = 0; w2 < 8; ++w2)
                    acc[u][w2] = fmaf(a[u], b[w2], acc[u][w2]);
        }
    }
#pragma unroll
    for (int u = 0; u < 8; ++u) {
        const int i = i0 + tr * 8 + u;
#pragma unroll
        for (int w2 = 0; w2 < 8; ++w2) {
            const int j = j0 + tc * 8 + w2;
            C[(size_t)i * D_ + j] = acc[u][w2] + B[j];
        }
    }
}

// ---------------------------------------------------------------------------
// Stripe A-GEMM: S[i][j] = scale*(Q_i . K_t), t = s0-1+j, j in [0,stride);
// t outside [0,N_) -> 0 (implements conv SAME zero-pad at global edges).
// ---------------------------------------------------------------------------
__global__ void __launch_bounds__(256, 2)
gemm_stripe(const float* __restrict__ Q, const float* __restrict__ K,
            const float* __restrict__ scp, float* __restrict__ S,
            int s0, int stride)
{
    __shared__ float XsT[32][132];
    __shared__ float WsT[32][132];
    const int tid = threadIdx.x;
    const int i0 = blockIdx.x * 128;
    const int j0 = blockIdx.y * 128;
    const int tr = tid >> 4, tc = tid & 15;
    float acc[8][8] = {};

    for (int k0 = 0; k0 < D_; k0 += 32) {
        __syncthreads();
#pragma unroll
        for (int p = 0; p < 16; ++p) {
            int idx = tid + p * 256;
            int r = idx >> 5, c = idx & 31;
            XsT[c][r] = Q[(size_t)(i0 + r) * D_ + (k0 + c)];
            int t = s0 - 1 + j0 + r;
            WsT[c][r] = ((unsigned)t < (unsigned)N_) ? K[(size_t)t * D_ + (k0 + c)] : 0.0f;
        }
        __syncthreads();
#pragma unroll
        for (int kk = 0; kk < 32; ++kk) {
            float a[8], b[8];
            *(float4*)&a[0] = *(const float4*)&XsT[kk][tr * 8];
            *(float4*)&a[4] = *(const float4*)&XsT[kk][tr * 8 + 4];
            *(float4*)&b[0] = *(const float4*)&WsT[kk][tc * 8];
            *(float4*)&b[4] = *(const float4*)&WsT[kk][tc * 8 + 4];
#pragma unroll
            for (int u = 0; u < 8; ++u)
#pragma unroll
                for (int w2 = 0; w2 < 8; ++w2)
                    acc[u][w2] = fmaf(a[u], b[w2], acc[u][w2]);
        }
    }
    const float s = scp[0];
#pragma unroll
    for (int u = 0; u < 8; ++u) {
        const size_t i = (size_t)(i0 + tr * 8 + u);
#pragma unroll
        for (int w2 = 0; w2 < 8; ++w2) {
            const int j = j0 + tc * 8 + w2;
            if (j < stride) S[i * stride + j] = acc[u][w2] * s;
        }
    }
}

// ---------------------------------------------------------------------------
// Fused conv3x3 + GEMM over one stripe:
//   attn[i][j] (+)= sum_{t in stripe} (conv(S)[i][t] + cb) * V[t][j]
// 64-row x 128-col output tiles, grid (128, 2); per 32-t chunk:
//   halo load (66 rows x 34 t) -> conv in regs -> 64x128x32 FMA GEMM.
// ---------------------------------------------------------------------------
__global__ void __launch_bounds__(256, 2)
conv_gemm_stripe(const float* __restrict__ S, const float* __restrict__ V,
                 const float* __restrict__ cw, const float* __restrict__ cb,
                 float* attn, int s0, int Wc, int stride, int first)
{
    __shared__ float AhT[34][68];   // [t-halo][row-halo]
    __shared__ float A4T[32][68];   // conv out [tt][r]
    __shared__ float Vs[32][132];   // [tt][c]
    const int tid = threadIdx.x;
    const int i0 = blockIdx.x * 64;
    const int j0 = blockIdx.y * 128;
    const int a = tid & 15, b = tid >> 4;        // conv ownership: 16 x 16
    const int tr2 = tid >> 5, tc2 = tid & 31;    // gemm: 8 x 32

    float wreg[9];
#pragma unroll
    for (int u = 0; u < 9; ++u) wreg[u] = cw[u];
    const float cbv = cb[0];

    float acc[8][4] = {};

    for (int tl = 0; tl < Wc; tl += 32) {
        __syncthreads();
        // halo: AhT[ct][rr] = S[i0-1+rr][tl+ct]; rows OOB -> 0
        for (int idx = tid; idx < 34 * 66; idx += 256) {
            int rr = idx / 34, ct = idx % 34;
            int gi = i0 - 1 + rr;
            AhT[ct][rr] = ((unsigned)gi < (unsigned)N_)
                            ? S[(size_t)gi * stride + (tl + ct)] : 0.0f;
        }
        // V chunk: Vs[tt][c] = V[s0+tl+tt][j0+c]
#pragma unroll
        for (int p = 0; p < 16; ++p) {
            int idx = tid + p * 256;
            int tt = idx >> 7, c = idx & 127;
            Vs[tt][c] = V[(size_t)(s0 + tl + tt) * D_ + (j0 + c)];
        }
        __syncthreads();
        // conv: thread -> A4T[2a+dt][4b+dr], dt in 0..1, dr in 0..3
        {
            float hreg[4][8];
#pragma unroll
            for (int v = 0; v < 4; ++v) {
                *(float4*)&hreg[v][0] = *(const float4*)&AhT[2 * a + v][4 * b];
                *(float4*)&hreg[v][4] = *(const float4*)&AhT[2 * a + v][4 * b + 4];
            }
#pragma unroll
            for (int dt = 0; dt < 2; ++dt) {
                float o[4];
#pragma unroll
                for (int dr = 0; dr < 4; ++dr) {
                    float s2 = cbv;
#pragma unroll
                    for (int u = 0; u < 3; ++u)
#pragma unroll
                        for (int v = 0; v < 3; ++v)
                            s2 = fmaf(wreg[u * 3 + v], hreg[dt + v][dr + u], s2);
                    o[dr] = s2;
                }
                *(float4*)&A4T[2 * a + dt][4 * b] = make_float4(o[0], o[1], o[2], o[3]);
            }
        }
        __syncthreads();
        // GEMM: acc += A4T[kk][row] * Vs[kk][col]
#pragma unroll
        for (int kk = 0; kk < 32; ++kk) {
            float av[8], bv4[4];
            *(float4*)&av[0] = *(const float4*)&A4T[kk][tr2 * 8];
            *(float4*)&av[4] = *(const float4*)&A4T[kk][tr2 * 8 + 4];
            *(float4*)&bv4[0] = *(const float4*)&Vs[kk][tc2 * 4];
#pragma unroll
            for (int u = 0; u < 8; ++u)
#pragma unroll
                for (int w2 = 0; w2 < 4; ++w2)
                    acc[u][w2] = fmaf(av[u], bv4[w2], acc[u][w2]);
        }
    }

#pragma unroll
    for (int u = 0; u < 8; ++u) {
        const size_t gi = (size_t)(i0 + tr2 * 8 + u);
#pragma unroll
        for (int w2 = 0; w2 < 4; ++w2) {
            const size_t idx = gi * D_ + (j0 + tc2 * 4 + w2);
            float prev = first ? 0.0f : attn[idx];
            attn[idx] = prev + acc[u][w2];
        }
    }
}

// ---------------------------------------------------------------------------
// Frobenius-norm reductions
// ---------------------------------------------------------------------------
__global__ void sumsq_partial(const float* __restrict__ Q, const float* __restrict__ K,
                              float* __restrict__ red)
{
    __shared__ float lds[8];
    const size_t base = (size_t)blockIdx.x * 8192;
    float sq = 0.0f, sk = 0.0f;
    for (int i = threadIdx.x; i < 8192; i += 256) {
        float a = Q[base + i]; sq = fmaf(a, a, sq);
        float b = K[base + i]; sk = fmaf(b, b, sk);
    }
#pragma unroll
    for (int o = 32; o > 0; o >>= 1) { sq += __shfl_down(sq, o); sk += __shfl_down(sk, o); }
    if ((threadIdx.x & 63) == 0) { lds[threadIdx.x >> 6] = sq; lds[4 + (threadIdx.x >> 6)] = sk; }
    __syncthreads();
    if (threadIdx.x == 0) {
        red[blockIdx.x]       = lds[0] + lds[1] + lds[2] + lds[3];
        red[256 + blockIdx.x] = lds[4] + lds[5] + lds[6] + lds[7];
    }
}

__global__ void finish_scale(const float* __restrict__ red, float* __restrict__ sc)
{
    __shared__ float lds[8];
    float sq = red[threadIdx.x];
    float sk = red[256 + threadIdx.x];
#pragma unroll
    for (int o = 32; o > 0; o >>= 1) { sq += __shfl_down(sq, o); sk += __shfl_down(sk, o); }
    if ((threadIdx.x & 63) == 0) { lds[threadIdx.x >> 6] = sq; lds[4 + (threadIdx.x >> 6)] = sk; }
    __syncthreads();
    if (threadIdx.x == 0) {
        float SQ = lds[0] + lds[1] + lds[2] + lds[3];
        float SK = lds[4] + lds[5] + lds[6] + lds[7];
        sc[0] = rsqrtf(SQ) * rsqrtf(SK);
    }
}

// ---------------------------------------------------------------------------
// h = x + LN1(attn) (in-place: attn/h both = d_out); l2 = LN2(h)
// ---------------------------------------------------------------------------
__device__ __forceinline__ float blockSum(float v, float* lds)
{
#pragma unroll
    for (int o = 32; o > 0; o >>= 1) v += __shfl_down(v, o);
    __syncthreads();
    if ((threadIdx.x & 63) == 0) lds[threadIdx.x >> 6] = v;
    __syncthreads();
    return lds[0] + lds[1] + lds[2] + lds[3];
}

__global__ void ln_fuse(const float* __restrict__ x, const float* attn,
                        const float* __restrict__ ln1g, const float* __restrict__ ln1b,
                        const float* __restrict__ ln2g, const float* __restrict__ ln2b,
                        float* h, float* __restrict__ l2)
{
    __shared__ float lds[4];
    const int t = threadIdx.x;
    const size_t off = (size_t)blockIdx.x * D_ + t;
    const float a = attn[off];
    const float m = blockSum(a, lds) * (1.0f / D_);
    const float d = a - m;
    const float var = blockSum(d * d, lds) * (1.0f / D_);
    const float hv = x[off] + d * rsqrtf(var + EPSF) * ln1g[t] + ln1b[t];
    h[off] = hv;
    const float m2 = blockSum(hv, lds) * (1.0f / D_);
    const float d2 = hv - m2;
    const float v2 = blockSum(d2 * d2, lds) * (1.0f / D_);
    l2[off] = d2 * rsqrtf(v2 + EPSF) * ln2g[t] + ln2b[t];
}

// ---------------------------------------------------------------------------
// z = l2 @ m1w^T (generic NT GEMM, Jd=128)
// ---------------------------------------------------------------------------
__global__ void __launch_bounds__(256, 2)
gemm_nt(const float* __restrict__ X, const float* __restrict__ W,
        float* __restrict__ C, int Kd, int Jd)
{
    __shared__ float XsT[32][132];
    __shared__ float WsT[32][132];
    const int tid = threadIdx.x;
    const int i0 = blockIdx.x * 128;
    const int j0 = blockIdx.y * 128;
    const int tr = tid >> 4, tc = tid & 15;
    float acc[8][8] = {};
    for (int k0 = 0; k0 < Kd; k0 += 32) {
        __syncthreads();
#pragma unroll
        for (int p = 0; p < 16; ++p) {
            int idx = tid + p * 256;
            int r = idx >> 5, c = idx & 31;
            XsT[c][r] = X[(size_t)(i0 + r) * Kd + (k0 + c)];
            WsT[c][r] = W[(size_t)(j0 + r) * Kd + (k0 + c)];
        }
        __syncthreads();
#pragma unroll
        for (int kk = 0; kk < 32; ++kk) {
            float a[8], b[8];
            *(float4*)&a[0] = *(const float4*)&XsT[kk][tr * 8];
            *(float4*)&a[4] = *(const float4*)&XsT[kk][tr * 8 + 4];
            *(float4*)&b[0] = *(const float4*)&WsT[kk][tc * 8];
            *(float4*)&b[4] = *(const float4*)&WsT[kk][tc * 8 + 4];
#pragma unroll
            for (int u = 0; u < 8; ++u)
#pragma unroll
                for (int w2 = 0; w2 < 8; ++w2)
                    acc[u][w2] = fmaf(a[u], b[w2], acc[u][w2]);
        }
    }
#pragma unroll
    for (int u = 0; u < 8; ++u) {
        const int i = i0 + tr * 8 + u;
#pragma unroll
        for (int w2 = 0; w2 < 8; ++w2)
            C[(size_t)i * Jd + (j0 + tc * 8 + w2)] = acc[u][w2];
    }
}

// ---------------------------------------------------------------------------
// BN stats per column of z
// ---------------------------------------------------------------------------
__global__ void bn_stats(const float* __restrict__ z, const float* __restrict__ bng,
                         const float* __restrict__ bnb,
                         float* __restrict__ bn_a, float* __restrict__ bn_b)
{
    __shared__ float lds[8];
    const int c = blockIdx.x;
    float s = 0.0f, sq = 0.0f;
    for (int r = threadIdx.x; r < N_; r += 256) {
        float zv = z[(size_t)r * H_ + c];
        s += zv; sq = fmaf(zv, zv, sq);
    }
#pragma unroll
    for (int o = 32; o > 0; o >>= 1) { s += __shfl_down(s, o); sq += __shfl_down(sq, o); }
    if ((threadIdx.x & 63) == 0) { lds[threadIdx.x >> 6] = s; lds[4 + (threadIdx.x >> 6)] = sq; }
    __syncthreads();
    if (threadIdx.x == 0) {
        float S  = lds[0] + lds[1] + lds[2] + lds[3];
        float SQ = lds[4] + lds[5] + lds[6] + lds[7];
        float mu = S * (1.0f / N_);
        float var = SQ * (1.0f / N_) - mu * mu;
        float aa = rsqrtf(var + EPSF) * bng[c];
        bn_a[c] = aa;
        bn_b[c] = bnb[c] - mu * aa;
    }
}

// ---------------------------------------------------------------------------
// out = h + relu(z*a+b) @ m2w^T   (h = out = d_out, in-place per element)
// ---------------------------------------------------------------------------
__global__ void __launch_bounds__(256, 2)
gemm_out(const float* __restrict__ Z, const float* __restrict__ W,
         const float* __restrict__ bn_a, const float* __restrict__ bn_b,
         const float* Hbuf, float* out)
{
    __shared__ float XsT[32][132];
    __shared__ float WsT[32][132];
    const int tid = threadIdx.x;
    const int i0 = blockIdx.x * 128;
    const int j0 = blockIdx.y * 128;
    const int tr = tid >> 4, tc = tid & 15;
    float acc[8][8] = {};
    for (int k0 = 0; k0 < H_; k0 += 32) {
        __syncthreads();
#pragma unroll
        for (int p = 0; p < 16; ++p) {
            int idx = tid + p * 256;
            int r = idx >> 5, c = idx & 31;
            float zv = Z[(size_t)(i0 + r) * H_ + (k0 + c)];
            XsT[c][r] = fmaxf(fmaf(zv, bn_a[k0 + c], bn_b[k0 + c]), 0.0f);
            WsT[c][r] = W[(size_t)(j0 + r) * H_ + (k0 + c)];
        }
        __syncthreads();
#pragma unroll
        for (int kk = 0; kk < 32; ++kk) {
            float a[8], b[8];
            *(float4*)&a[0] = *(const float4*)&XsT[kk][tr * 8];
            *(float4*)&a[4] = *(const float4*)&XsT[kk][tr * 8 + 4];
            *(float4*)&b[0] = *(const float4*)&WsT[kk][tc * 8];
            *(float4*)&b[4] = *(const float4*)&WsT[kk][tc * 8 + 4];
#pragma unroll
            for (int u = 0; u < 8; ++u)
#pragma unroll
                for (int w2 = 0; w2 < 8; ++w2)
                    acc[u][w2] = fmaf(a[u], b[w2], acc[u][w2]);
        }
    }
#pragma unroll
    for (int u = 0; u < 8; ++u) {
        const int i = i0 + tr * 8 + u;
#pragma unroll
        for (int w2 = 0; w2 < 8; ++w2) {
            const int j = j0 + tc * 8 + w2;
            out[(size_t)i * D_ + j] = Hbuf[(size_t)i * D_ + j] + acc[u][w2];
        }
    }
}

// ---------------------------------------------------------------------------
extern "C" void kernel_launch(void* const* d_in, const int* in_sizes, int n_in,
                              void* d_out, int out_size, void* d_ws, size_t ws_size,
                              hipStream_t stream)
{
    const float* x    = (const float*)d_in[0];
    const float* wq   = (const float*)d_in[1];
    const float* bq   = (const float*)d_in[2];
    const float* wk   = (const float*)d_in[3];
    const float* bk   = (const float*)d_in[4];
    const float* wv   = (const float*)d_in[5];
    const float* bv   = (const float*)d_in[6];
    const float* cw   = (const float*)d_in[7];
    const float* cb   = (const float*)d_in[8];
    const float* m1w  = (const float*)d_in[9];
    const float* m2w  = (const float*)d_in[10];
    const float* bng  = (const float*)d_in[11];
    const float* bnb  = (const float*)d_in[12];
    const float* ln1g = (const float*)d_in[13];
    const float* ln1b = (const float*)d_in[14];
    const float* ln2g = (const float*)d_in[15];
    const float* ln2b = (const float*)d_in[16];

    float* outF = (float*)d_out;
    float* ws   = (float*)d_ws;

    // workspace-adaptive stripe width (multiple of 32, +2 halo cols fit)
    const size_t wsf = ws_size / sizeof(float);
    if (wsf < OFF_STRIPE + (size_t)N_ * 34) return;       // cannot run at all
    const size_t colsmax = (wsf - OFF_STRIPE) / (size_t)N_; // max stride (W+2)
    int Wst = (int)((colsmax - 2) & ~(size_t)31);
    if (Wst > N_) Wst = N_;

    float* Q   = ws;                 // later reused as L2
    float* Kb  = ws + NF;            // later reused as Z
    float* V   = ws + 2 * NF;
    float* RED = ws + OFF_RED;
    float* SC  = ws + OFF_SC;
    float* BNA = ws + OFF_BNA;
    float* BNB = ws + OFF_BNB;
    float* STR = ws + OFF_STRIPE;
    float* L2  = Q;
    float* Z   = Kb;

    const dim3 b256(256);

    // 1. q,k,v (fused)
    qkv_nt<<<dim3(64, 6), b256, 0, stream>>>(x, wq, bq, wk, bk, wv, bv, Q);
    // 2. scale
    sumsq_partial<<<256, b256, 0, stream>>>(Q, Kb, RED);
    finish_scale<<<1, b256, 0, stream>>>(RED, SC);
    // 3. striped A + fused conv/GEMM, accumulating attn into d_out
    for (int s0 = 0; s0 < N_; s0 += Wst) {
        int Wc = (N_ - s0 < Wst) ? (N_ - s0) : Wst;
        int stride = Wc + 2;
        gemm_stripe<<<dim3(64, (stride + 127) / 128), b256, 0, stream>>>(
            Q, Kb, SC, STR, s0, stride);
        conv_gemm_stripe<<<dim3(128, 2), b256, 0, stream>>>(
            STR, V, cw, cb, outF, s0, Wc, stride, (s0 == 0) ? 1 : 0);
    }
    // 4. h = x + LN1(attn) (in d_out, in place); l2 = LN2(h)
    ln_fuse<<<N_, b256, 0, stream>>>(x, outF, ln1g, ln1b, ln2g, ln2b, outF, L2);
    // 5. z = l2 @ m1w^T
    gemm_nt<<<dim3(64, 1), b256, 0, stream>>>(L2, m1w, Z, D_, H_);
    // 6. BN stats
    bn_stats<<<H_, b256, 0, stream>>>(Z, bng, bnb, BNA, BNB);
    // 7. out = h + relu(z*a+b) @ m2w^T  (in place over d_out)
    gemm_out<<<dim3(64, 2), b256, 0, stream>>>(Z, m2w, BNA, BNB, outF, outF);
}

// Round 5
// 186.179 us; speedup vs baseline: 15.3254x; 15.3254x over previous
//
#include <hip/hip_runtime.h>
#include <hip/hip_bf16.h>
#include <math.h>

// ---------------------------------------------------------------------------
// GraphBased_selfAttnLayer — algebraically collapsed attention path.
//
// attn = A4 @ v with A4 = conv3x3(q_n k_n^T) + cb collapses (bilinearity of
// conv, rank-D factorization) to:
//   G_v  = (S_{v-1} K)^T V                (3x [256x256], K-dim 8192, MFMA)
//   M_u  = scale * sum_v cw[u][v] G_v     (scale = 1/(||q||F ||k||F))
//   attn = sum_u S_{u-1}(Q M_u) + cb*colsum(V)   (MFMA, row-shifts via guard)
// Then: h = x + LN1(attn); l2 = LN2(h); z = l2@m1w^T; BN; out = h + relu@m2w^T
//
// ws (bytes):
//   QbG  bf16 [8194][256] (guard rows)     @ 0
//   Kb   bf16 [8192][256]                  @ 4,195,328   (aliased later by L2)
//   KTb  bf16 [256][8192]                  @ 8,389,632   (aliased later by L2)
//   VbG  bf16 [8194][256] (guard rows)     @ 12,583,936
//   Gpart f32 [24][256][256]               @ 16,779,264  (aliased later by Z)
//   MTb  bf16 [3][256 j][256 d]            @ 23,070,720
//   SVpart f32 [64][256]                   @ 23,463,936
//   SVC  f32 [256]                         @ 23,529,472
//   RED  f32 [512]                         @ 23,530,496
//   SC   f32 [16]                          @ 23,532,544
//   BNA/BNB f32 [128][128]                 @ 23,532,608
// total ~23.54 MB  (< 26.3 MB proven available in round 3)
// ---------------------------------------------------------------------------

#define N_ 8192
#define D_ 256
#define H_ 128
#define EPSF 1e-5f

typedef unsigned short ushort_t;
typedef __attribute__((ext_vector_type(8))) short bf16x8;
typedef __attribute__((ext_vector_type(4))) float f32x4;

static const size_t OFF_QB  = 0;
static const size_t OFF_KB  = 4195328;
static const size_t OFF_KT  = 8389632;
static const size_t OFF_VB  = 12583936;
static const size_t OFF_GP  = 16779264;
static const size_t OFF_MT  = 23070720;
static const size_t OFF_SVP = 23463936;
static const size_t OFF_SVC = 23529472;
static const size_t OFF_RED = 23530496;
static const size_t OFF_SC  = 23532544;
static const size_t OFF_BNA = 23532608;
static const size_t OFF_BNB = 23533120;
static const size_t WS_NEED = 23533632;
// aliases: L2 (f32 [8192][256], 8.39MB) over Kb+KTb; Z (f32 [8192][128]) over Gpart

__device__ __forceinline__ ushort_t f2bf(float f) {
    __hip_bfloat16 h = __float2bfloat16(f);
    return reinterpret_cast<ushort_t&>(h);
}

// ---------------------------------------------------------------------------
// zero the guard rows of QbG / VbG (rows 0 and 8193 in guarded coords)
// ---------------------------------------------------------------------------
__global__ void zero_guards(ushort_t* qb, ushort_t* vb)
{
    const int t = threadIdx.x;  // 256
    qb[t] = 0; qb[(size_t)8193 * 256 + t] = 0;
    vb[t] = 0; vb[(size_t)8193 * 256 + t] = 0;
}

// ---------------------------------------------------------------------------
// Fused q/k/v GEMM (fp32 VALU): blockIdx.y: sel = y>>1 (q/k/v), y&1 col half.
// Writes bf16 outputs (Qb guarded, Kb, Vb guarded) + sumsq partials (q,k)
// + column-sum partials (v).
// ---------------------------------------------------------------------------
__global__ void __launch_bounds__(256, 2)
qkv_nt(const float* __restrict__ x,
       const float* __restrict__ wq, const float* __restrict__ bq,
       const float* __restrict__ wk, const float* __restrict__ bk,
       const float* __restrict__ wv, const float* __restrict__ bv,
       ushort_t* __restrict__ QbG, ushort_t* __restrict__ Kb,
       ushort_t* __restrict__ VbG,
       float* __restrict__ RED, float* __restrict__ SVpart)
{
    __shared__ float XsT[32][132];
    __shared__ float WsT[32][132];
    __shared__ float cs[128];
    __shared__ float lds4[4];
    const int sel = blockIdx.y >> 1;
    const float* W = (sel == 0) ? wq : ((sel == 1) ? wk : wv);
    const float* B = (sel == 0) ? bq : ((sel == 1) ? bk : bv);
    const int tid = threadIdx.x;
    const int i0 = blockIdx.x * 128;
    const int j0 = (blockIdx.y & 1) * 128;
    const int tr = tid >> 4, tc = tid & 15;
    float acc[8][8] = {};

    for (int k0 = 0; k0 < D_; k0 += 32) {
        __syncthreads();
#pragma unroll
        for (int p = 0; p < 16; ++p) {
            int idx = tid + p * 256;
            int r = idx >> 5, c = idx & 31;
            XsT[c][r] = x[(size_t)(i0 + r) * D_ + (k0 + c)];
            WsT[c][r] = W[(size_t)(j0 + r) * D_ + (k0 + c)];
        }
        __syncthreads();
#pragma unroll
        for (int kk = 0; kk < 32; ++kk) {
            float a[8], b[8];
            *(float4*)&a[0] = *(const float4*)&XsT[kk][tr * 8];
            *(float4*)&a[4] = *(const float4*)&XsT[kk][tr * 8 + 4];
            *(float4*)&b[0] = *(const float4*)&WsT[kk][tc * 8];
            *(float4*)&b[4] = *(const float4*)&WsT[kk][tc * 8 + 4];
#pragma unroll
            for (int u = 0; u < 8; ++u)
#pragma unroll
                for (int w2 = 0; w2 < 8; ++w2)
                    acc[u][w2] = fmaf(a[u], b[w2], acc[u][w2]);
        }
    }

    // epilogue: add bias, write bf16, side reductions
    float ssq = 0.0f;
    float colpart[8];
#pragma unroll
    for (int w2 = 0; w2 < 8; ++w2) colpart[w2] = 0.0f;

    ushort_t* dst = (sel == 0) ? (QbG + 256) : ((sel == 1) ? Kb : (VbG + 256));
#pragma unroll
    for (int u = 0; u < 8; ++u) {
        const int i = i0 + tr * 8 + u;
#pragma unroll
        for (int w2 = 0; w2 < 8; ++w2) {
            const int j = j0 + tc * 8 + w2;
            float val = acc[u][w2] + B[j];
            dst[(size_t)i * D_ + j] = f2bf(val);
            ssq = fmaf(val, val, ssq);
            colpart[w2] += val;
        }
    }

    if (sel < 2) {
        float s = ssq;
#pragma unroll
        for (int o = 32; o > 0; o >>= 1) s += __shfl_down(s, o);
        if ((tid & 63) == 0) lds4[tid >> 6] = s;
        __syncthreads();
        if (tid == 0)
            RED[sel * 128 + blockIdx.x * 2 + (blockIdx.y & 1)]
                = lds4[0] + lds4[1] + lds4[2] + lds4[3];
    } else {
        if (tid < 128) cs[tid] = 0.0f;
        __syncthreads();
        for (int r = 0; r < 16; ++r) {
            if (tr == r) {
#pragma unroll
                for (int w2 = 0; w2 < 8; ++w2) cs[tc * 8 + w2] += colpart[w2];
            }
            __syncthreads();
        }
        if (tid < 128)
            SVpart[(size_t)blockIdx.x * 256 + (blockIdx.y & 1) * 128 + tid] = cs[tid];
    }
}

// ---------------------------------------------------------------------------
// KTb[d][t] = Kb[t][d]  (bf16 32x32 LDS transpose)
// ---------------------------------------------------------------------------
__global__ void transpose_k(const ushort_t* __restrict__ Kb, ushort_t* __restrict__ KT)
{
    __shared__ ushort_t tile[32][33];
    const int tid = threadIdx.x;
    const int t0 = blockIdx.x * 32, d0 = blockIdx.y * 32;
#pragma unroll
    for (int p = 0; p < 4; ++p) {
        int idx = tid + p * 256;
        int r = idx >> 5, c = idx & 31;
        tile[r][c] = Kb[(size_t)(t0 + r) * 256 + d0 + c];
    }
    __syncthreads();
#pragma unroll
    for (int p = 0; p < 4; ++p) {
        int idx = tid + p * 256;
        int r = idx >> 5, c = idx & 31;
        KT[(size_t)(d0 + r) * 8192 + t0 + c] = tile[c][r];
    }
}

// ---------------------------------------------------------------------------
// scale = 1/(||q|| ||k||);  SVC[j] = cb * sum_t V[t][j]
// ---------------------------------------------------------------------------
__global__ void finish_scale_sv(const float* __restrict__ RED,
                                const float* __restrict__ SVpart,
                                const float* __restrict__ cb,
                                float* __restrict__ SC, float* __restrict__ SVC)
{
    __shared__ float lds[8];
    const int t = threadIdx.x;
    float sq = (t < 128) ? RED[t] : 0.0f;
    float sk = (t < 128) ? RED[128 + t] : 0.0f;
#pragma unroll
    for (int o = 32; o > 0; o >>= 1) { sq += __shfl_down(sq, o); sk += __shfl_down(sk, o); }
    if ((t & 63) == 0) { lds[t >> 6] = sq; lds[4 + (t >> 6)] = sk; }
    __syncthreads();
    if (t == 0) {
        float SQ = lds[0] + lds[1] + lds[2] + lds[3];
        float SK = lds[4] + lds[5] + lds[6] + lds[7];
        SC[0] = rsqrtf(SQ) * rsqrtf(SK);
    }
    float s = 0.0f;
    for (int bx = 0; bx < 64; ++bx) s += SVpart[(size_t)bx * 256 + t];
    SVC[t] = cb[0] * s;
}

// ---------------------------------------------------------------------------
// G_v[d][j] = sum_t K[t][d] * V[t+1-v][j]   (v-shift on V via guard rows)
// grid (2, 2, 24): z = ks*3+v, ks in 0..7 (t-chunks of 1024). MFMA 16x16x32.
// A = KTb (contiguous frags), B = VbG (8 row-strided ushort loads per frag).
// ---------------------------------------------------------------------------
__global__ void __launch_bounds__(256)
g_mfma(const ushort_t* __restrict__ KT, const ushort_t* __restrict__ VbG,
       float* __restrict__ Gpart)
{
    const int tid = threadIdx.x, lane = tid & 63, wid = tid >> 6;
    const int wr = wid >> 1, wc = wid & 1;
    const int d0 = blockIdx.x * 128 + wr * 64;
    const int j0 = blockIdx.y * 128 + wc * 64;
    const int z = blockIdx.z, ks = z / 3, v = z - ks * 3;
    const int tbase = ks * 1024;
    const int l15 = lane & 15, kg = lane >> 4;

    f32x4 acc[4][4];
#pragma unroll
    for (int mi = 0; mi < 4; ++mi)
#pragma unroll
        for (int ni = 0; ni < 4; ++ni) acc[mi][ni] = 0.0f;

    for (int tt = 0; tt < 1024; tt += 32) {
        const int t0 = tbase + tt;
        bf16x8 a[4];
#pragma unroll
        for (int mi = 0; mi < 4; ++mi)
            a[mi] = *(const bf16x8*)(KT + (size_t)(d0 + 16 * mi + l15) * 8192 + t0 + 8 * kg);
#pragma unroll
        for (int ni = 0; ni < 4; ++ni) {
            bf16x8 b;
            const ushort_t* vp = VbG + (size_t)(t0 + 8 * kg + 2 - v) * 256
                                     + (j0 + 16 * ni + l15);
#pragma unroll
            for (int e = 0; e < 8; ++e) b[e] = (short)vp[(size_t)e * 256];
#pragma unroll
            for (int mi = 0; mi < 4; ++mi)
                acc[mi][ni] = __builtin_amdgcn_mfma_f32_16x16x32_bf16(a[mi], b, acc[mi][ni], 0, 0, 0);
        }
    }

    float* gp = Gpart + (size_t)z * 65536;
#pragma unroll
    for (int mi = 0; mi < 4; ++mi)
#pragma unroll
        for (int ni = 0; ni < 4; ++ni)
#pragma unroll
            for (int r = 0; r < 4; ++r)
                gp[(size_t)(d0 + 16 * mi + 4 * kg + r) * 256 + (j0 + 16 * ni + l15)]
                    = acc[mi][ni][r];
}

// ---------------------------------------------------------------------------
// MTb[u][j][d] = scale * sum_v cw[u][v] * (sum_ks Gpart[ks*3+v][d][j])  (bf16)
// grid 256 (block = d), 256 threads (thread = j): coalesced Gpart reads.
// ---------------------------------------------------------------------------
__global__ void combine_m(const float* __restrict__ Gpart, const float* __restrict__ cw,
                          const float* __restrict__ SC, ushort_t* __restrict__ MT)
{
    const int d = blockIdx.x, j = threadIdx.x;
    float g[3] = {0.0f, 0.0f, 0.0f};
    for (int ks = 0; ks < 8; ++ks)
#pragma unroll
        for (int v = 0; v < 3; ++v)
            g[v] += Gpart[(size_t)(ks * 3 + v) * 65536 + (size_t)d * 256 + j];
    const float sc = SC[0];
#pragma unroll
    for (int u = 0; u < 3; ++u) {
        float m = sc * (cw[u * 3 + 0] * g[0] + cw[u * 3 + 1] * g[1] + cw[u * 3 + 2] * g[2]);
        MT[(size_t)u * 65536 + (size_t)j * 256 + d] = f2bf(m);
    }
}

// ---------------------------------------------------------------------------
// attn[i][j] = sum_u sum_d Q[i+u-1][d] MT_u[j][d]  + SVC[j]
// grid (128, 2): 64-row x 128-col tiles, 4 waves each own 32 cols.
// Pure L2->VGPR->MFMA (no LDS, no barriers). u-shift = aligned row offset.
// ---------------------------------------------------------------------------
__global__ void __launch_bounds__(256)
attn_mfma(const ushort_t* __restrict__ QbG, const ushort_t* __restrict__ MT,
          const float* __restrict__ SVC, float* __restrict__ attn)
{
    const int tid = threadIdx.x, lane = tid & 63, wid = tid >> 6;
    const int i0 = blockIdx.x * 64;
    const int jw = blockIdx.y * 128 + wid * 32;
    const int l15 = lane & 15, kg = lane >> 4;

    f32x4 acc[4][2];
#pragma unroll
    for (int mi = 0; mi < 4; ++mi) { acc[mi][0] = 0.0f; acc[mi][1] = 0.0f; }

    for (int k0 = 0; k0 < 256; k0 += 32) {
        bf16x8 a[3][4], b[3][2];
#pragma unroll
        for (int u = 0; u < 3; ++u)
#pragma unroll
            for (int mi = 0; mi < 4; ++mi)
                a[u][mi] = *(const bf16x8*)(QbG
                    + (size_t)(i0 + 16 * mi + l15 + u) * 256 + k0 + 8 * kg);
#pragma unroll
        for (int u = 0; u < 3; ++u)
#pragma unroll
            for (int ni = 0; ni < 2; ++ni)
                b[u][ni] = *(const bf16x8*)(MT + (size_t)u * 65536
                    + (size_t)(jw + 16 * ni + l15) * 256 + k0 + 8 * kg);
#pragma unroll
        for (int mi = 0; mi < 4; ++mi)
#pragma unroll
            for (int ni = 0; ni < 2; ++ni)
#pragma unroll
                for (int u = 0; u < 3; ++u)
                    acc[mi][ni] = __builtin_amdgcn_mfma_f32_16x16x32_bf16(
                        a[u][mi], b[u][ni], acc[mi][ni], 0, 0, 0);
    }

    float sv[2];
    sv[0] = SVC[jw + l15];
    sv[1] = SVC[jw + 16 + l15];
#pragma unroll
    for (int mi = 0; mi < 4; ++mi)
#pragma unroll
        for (int ni = 0; ni < 2; ++ni)
#pragma unroll
            for (int r = 0; r < 4; ++r)
                attn[(size_t)(i0 + 16 * mi + 4 * kg + r) * 256 + (jw + 16 * ni + l15)]
                    = acc[mi][ni][r] + sv[ni];
}

// ---------------------------------------------------------------------------
// h = x + LN1(attn) (in-place in d_out); l2 = LN2(h)
// ---------------------------------------------------------------------------
__device__ __forceinline__ float blockSum(float v, float* lds)
{
#pragma unroll
    for (int o = 32; o > 0; o >>= 1) v += __shfl_down(v, o);
    __syncthreads();
    if ((threadIdx.x & 63) == 0) lds[threadIdx.x >> 6] = v;
    __syncthreads();
    return lds[0] + lds[1] + lds[2] + lds[3];
}

__global__ void ln_fuse(const float* __restrict__ x, const float* attn,
                        const float* __restrict__ ln1g, const float* __restrict__ ln1b,
                        const float* __restrict__ ln2g, const float* __restrict__ ln2b,
                        float* h, float* __restrict__ l2)
{
    __shared__ float lds[4];
    const int t = threadIdx.x;
    const size_t off = (size_t)blockIdx.x * D_ + t;
    const float a = attn[off];
    const float m = blockSum(a, lds) * (1.0f / D_);
    const float d = a - m;
    const float var = blockSum(d * d, lds) * (1.0f / D_);
    const float hv = x[off] + d * rsqrtf(var + EPSF) * ln1g[t] + ln1b[t];
    h[off] = hv;
    const float m2 = blockSum(hv, lds) * (1.0f / D_);
    const float d2 = hv - m2;
    const float v2 = blockSum(d2 * d2, lds) * (1.0f / D_);
    l2[off] = d2 * rsqrtf(v2 + EPSF) * ln2g[t] + ln2b[t];
}

// ---------------------------------------------------------------------------
// z = l2 @ m1w^T : 32x128 tiles, grid (256,1)
// ---------------------------------------------------------------------------
__global__ void __launch_bounds__(256, 2)
gemm_z32(const float* __restrict__ X, const float* __restrict__ W, float* __restrict__ C)
{
    __shared__ float XsT[32][36];
    __shared__ float WsT[32][132];
    const int tid = threadIdx.x;
    const int i0 = blockIdx.x * 32;
    const int tr = tid >> 4, tc = tid & 15;
    float acc[2][8] = {};
    for (int k0 = 0; k0 < 256; k0 += 32) {
        __syncthreads();
#pragma unroll
        for (int p = 0; p < 4; ++p) {
            int idx = tid + p * 256;
            int r = idx >> 5, c = idx & 31;
            XsT[c][r] = X[(size_t)(i0 + r) * 256 + k0 + c];
        }
#pragma unroll
        for (int p = 0; p < 16; ++p) {
            int idx = tid + p * 256;
            int r = idx >> 5, c = idx & 31;
            WsT[c][r] = W[(size_t)r * 256 + k0 + c];
        }
        __syncthreads();
#pragma unroll
        for (int kk = 0; kk < 32; ++kk) {
            float a0 = XsT[kk][tr * 2], a1 = XsT[kk][tr * 2 + 1];
            float b[8];
            *(float4*)&b[0] = *(const float4*)&WsT[kk][tc * 8];
            *(float4*)&b[4] = *(const float4*)&WsT[kk][tc * 8 + 4];
#pragma unroll
            for (int w2 = 0; w2 < 8; ++w2) {
                acc[0][w2] = fmaf(a0, b[w2], acc[0][w2]);
                acc[1][w2] = fmaf(a1, b[w2], acc[1][w2]);
            }
        }
    }
#pragma unroll
    for (int u = 0; u < 2; ++u)
#pragma unroll
        for (int w2 = 0; w2 < 8; ++w2)
            C[(size_t)(i0 + tr * 2 + u) * 128 + tc * 8 + w2] = acc[u][w2];
}

// ---------------------------------------------------------------------------
// BN stats per column of z
// ---------------------------------------------------------------------------
__global__ void bn_stats(const float* __restrict__ z, const float* __restrict__ bng,
                         const float* __restrict__ bnb,
                         float* __restrict__ bn_a, float* __restrict__ bn_b)
{
    __shared__ float lds[8];
    const int c = blockIdx.x;
    float s = 0.0f, sq = 0.0f;
    for (int r = threadIdx.x; r < N_; r += 256) {
        float zv = z[(size_t)r * H_ + c];
        s += zv; sq = fmaf(zv, zv, sq);
    }
#pragma unroll
    for (int o = 32; o > 0; o >>= 1) { s += __shfl_down(s, o); sq += __shfl_down(sq, o); }
    if ((threadIdx.x & 63) == 0) { lds[threadIdx.x >> 6] = s; lds[4 + (threadIdx.x >> 6)] = sq; }
    __syncthreads();
    if (threadIdx.x == 0) {
        float S  = lds[0] + lds[1] + lds[2] + lds[3];
        float SQ = lds[4] + lds[5] + lds[6] + lds[7];
        float mu = S * (1.0f / N_);
        float var = SQ * (1.0f / N_) - mu * mu;
        float aa = rsqrtf(var + EPSF) * bng[c];
        bn_a[c] = aa;
        bn_b[c] = bnb[c] - mu * aa;
    }
}

// ---------------------------------------------------------------------------
// out = h + relu(z*a+b) @ m2w^T : 32x128 tiles, grid (256,2), in-place over d_out
// ---------------------------------------------------------------------------
__global__ void __launch_bounds__(256, 2)
gemm_out32(const float* __restrict__ Z, const float* __restrict__ W,
           const float* __restrict__ bn_a, const float* __restrict__ bn_b,
           const float* Hbuf, float* out)
{
    __shared__ float XsT[32][36];
    __shared__ float WsT[32][132];
    const int tid = threadIdx.x;
    const int i0 = blockIdx.x * 32;
    const int j0 = blockIdx.y * 128;
    const int tr = tid >> 4, tc = tid & 15;
    float acc[2][8] = {};
    for (int k0 = 0; k0 < 128; k0 += 32) {
        __syncthreads();
#pragma unroll
        for (int p = 0; p < 4; ++p) {
            int idx = tid + p * 256;
            int r = idx >> 5, c = idx & 31;
            float zv = Z[(size_t)(i0 + r) * 128 + k0 + c];
            XsT[c][r] = fmaxf(fmaf(zv, bn_a[k0 + c], bn_b[k0 + c]), 0.0f);
        }
#pragma unroll
        for (int p = 0; p < 16; ++p) {
            int idx = tid + p * 256;
            int r = idx >> 5, c = idx & 31;
            WsT[c][r] = W[(size_t)(j0 + r) * 128 + k0 + c];
        }
        __syncthreads();
#pragma unroll
        for (int kk = 0; kk < 32; ++kk) {
            float a0 = XsT[kk][tr * 2], a1 = XsT[kk][tr * 2 + 1];
            float b[8];
            *(float4*)&b[0] = *(const float4*)&WsT[kk][tc * 8];
            *(float4*)&b[4] = *(const float4*)&WsT[kk][tc * 8 + 4];
#pragma unroll
            for (int w2 = 0; w2 < 8; ++w2) {
                acc[0][w2] = fmaf(a0, b[w2], acc[0][w2]);
                acc[1][w2] = fmaf(a1, b[w2], acc[1][w2]);
            }
        }
    }
#pragma unroll
    for (int u = 0; u < 2; ++u) {
        const size_t i = (size_t)(i0 + tr * 2 + u);
#pragma unroll
        for (int w2 = 0; w2 < 8; ++w2) {
            const size_t idx = i * 256 + j0 + tc * 8 + w2;
            out[idx] = Hbuf[idx] + acc[u][w2];
        }
    }
}

// ---------------------------------------------------------------------------
extern "C" void kernel_launch(void* const* d_in, const int* in_sizes, int n_in,
                              void* d_out, int out_size, void* d_ws, size_t ws_size,
                              hipStream_t stream)
{
    const float* x    = (const float*)d_in[0];
    const float* wq   = (const float*)d_in[1];
    const float* bq   = (const float*)d_in[2];
    const float* wk   = (const float*)d_in[3];
    const float* bk   = (const float*)d_in[4];
    const float* wv   = (const float*)d_in[5];
    const float* bv   = (const float*)d_in[6];
    const float* cw   = (const float*)d_in[7];
    const float* cb   = (const float*)d_in[8];
    const float* m1w  = (const float*)d_in[9];
    const float* m2w  = (const float*)d_in[10];
    const float* bng  = (const float*)d_in[11];
    const float* bnb  = (const float*)d_in[12];
    const float* ln1g = (const float*)d_in[13];
    const float* ln1b = (const float*)d_in[14];
    const float* ln2g = (const float*)d_in[15];
    const float* ln2b = (const float*)d_in[16];

    float* outF = (float*)d_out;
    char*  wsb  = (char*)d_ws;
    if (ws_size < WS_NEED) return;

    ushort_t* QbG = (ushort_t*)(wsb + OFF_QB);
    ushort_t* Kb  = (ushort_t*)(wsb + OFF_KB);
    ushort_t* KT  = (ushort_t*)(wsb + OFF_KT);
    ushort_t* VbG = (ushort_t*)(wsb + OFF_VB);
    float*    GP  = (float*)(wsb + OFF_GP);
    ushort_t* MT  = (ushort_t*)(wsb + OFF_MT);
    float*    SVP = (float*)(wsb + OFF_SVP);
    float*    SVC = (float*)(wsb + OFF_SVC);
    float*    RED = (float*)(wsb + OFF_RED);
    float*    SC  = (float*)(wsb + OFF_SC);
    float*    BNA = (float*)(wsb + OFF_BNA);
    float*    BNB = (float*)(wsb + OFF_BNB);
    float*    L2  = (float*)(wsb + OFF_KB);   // alias over Kb+KTb (dead)
    float*    Z   = (float*)(wsb + OFF_GP);   // alias over Gpart (dead)

    const dim3 b256(256);

    zero_guards<<<1, b256, 0, stream>>>(QbG, VbG);
    qkv_nt<<<dim3(64, 6), b256, 0, stream>>>(x, wq, bq, wk, bk, wv, bv,
                                             QbG, Kb, VbG, RED, SVP);
    transpose_k<<<dim3(256, 8), b256, 0, stream>>>(Kb, KT);
    finish_scale_sv<<<1, b256, 0, stream>>>(RED, SVP, cb, SC, SVC);
    g_mfma<<<dim3(2, 2, 24), b256, 0, stream>>>(KT, VbG, GP);
    combine_m<<<256, b256, 0, stream>>>(GP, cw, SC, MT);
    attn_mfma<<<dim3(128, 2), b256, 0, stream>>>(QbG, MT, SVC, outF);
    ln_fuse<<<N_, b256, 0, stream>>>(x, outF, ln1g, ln1b, ln2g, ln2b, outF, L2);
    gemm_z32<<<dim3(256, 1), b256, 0, stream>>>(L2, m1w, Z);
    bn_stats<<<H_, b256, 0, stream>>>(Z, bng, bnb, BNA, BNB);
    gemm_out32<<<dim3(256, 2), b256, 0, stream>>>(Z, m2w, BNA, BNB, outF, outF);
}

// Round 6
// 154.786 us; speedup vs baseline: 18.4336x; 1.2028x over previous
//
#include <hip/hip_runtime.h>
#include <hip/hip_bf16.h>
#include <math.h>

// ---------------------------------------------------------------------------
// GraphBased_selfAttnLayer — collapsed attention path, MFMA everywhere big.
//
//   G_v  = (S_{v-1} K)^T V                (3x [256x256], K-dim 8192, MFMA)
//   M_u  = scale * sum_v cw[u][v] G_v     (scale = 1/(||q||F ||k||F))
//   attn = sum_u S_{u-1}(Q M_u) + cb*colsum(V)   (MFMA, row-shifts via guard)
// Then: h = x + LN1(attn); l2 = LN2(h); z = l2@m1w^T; BN; out = h + relu@m2w^T
//
// ws layout (bytes):
//   QbG  bf16 [8194][256]          @ 0
//   Kb   bf16 [8192][256]          @  4,195,328   (later aliased by L2)
//   KTb  bf16 [256][8192]          @  8,389,632   (later aliased by L2)
//   VbG  bf16 [8194][256]          @ 12,583,936
//   GP   f32 [24][256][256]        @ 16,779,264   (xb aliases first 4MB; Z later)
//   MTb  bf16 [3][256][256]        @ 23,070,720
//   SVP  f32 [128][256]            @ 23,463,936
//   SVC  f32 [256]                 @ 23,595,008
//   RED  f32 [256+pad]             @ 23,596,032
//   SC   f32 [16]                  @ 23,598,080
//   BNA  f32 [128]                 @ 23,598,144
//   BNB  f32 [128]                 @ 23,598,656
//   WB   bf16 [3][256][256]        @ 23,599,168
//   BSP  f32 [64][2][128]          @ 23,992,384   (ends 24,057,920)
// total ~24.06 MB (< 26.3 MB proven available)
// ---------------------------------------------------------------------------

#define N_ 8192
#define D_ 256
#define H_ 128
#define EPSF 1e-5f

typedef unsigned short ushort_t;
typedef __attribute__((ext_vector_type(8))) short bf16x8;
typedef __attribute__((ext_vector_type(4))) float f32x4;

static const size_t OFF_QB  = 0;
static const size_t OFF_KB  = 4195328;
static const size_t OFF_KT  = 8389632;
static const size_t OFF_VB  = 12583936;
static const size_t OFF_GP  = 16779264;
static const size_t OFF_MT  = 23070720;
static const size_t OFF_SVP = 23463936;
static const size_t OFF_SVC = 23595008;
static const size_t OFF_RED = 23596032;
static const size_t OFF_SC  = 23598080;
static const size_t OFF_BNA = 23598144;
static const size_t OFF_BNB = 23598656;
static const size_t OFF_WB  = 23599168;
static const size_t OFF_BSP = 23992384;
static const size_t WS_NEED = 24057920;
// aliases: xb bf16 [8192][256] over GP (dead before g_mfma writes GP);
//          L2 f32 [8192][256] over Kb+KT (dead after g_mfma);
//          Z  f32 [8192][128] over GP (dead after combine_m).

__device__ __forceinline__ ushort_t f2bf(float f) {
    __hip_bfloat16 h = __float2bfloat16(f);
    return reinterpret_cast<ushort_t&>(h);
}

// ---------------------------------------------------------------------------
// prep: x -> bf16 (xb), wq/wk/wv -> bf16 (WB), zero guard rows of QbG/VbG.
// grid 1121 x 256 threads; 8 elems/thread.
// ---------------------------------------------------------------------------
__global__ void prep(const float* __restrict__ x,
                     const float* __restrict__ wq, const float* __restrict__ wk,
                     const float* __restrict__ wv,
                     ushort_t* __restrict__ xb, ushort_t* __restrict__ wb,
                     ushort_t* __restrict__ QbG, ushort_t* __restrict__ VbG)
{
    const int bid = blockIdx.x, tid = threadIdx.x;
    if (bid < 1024) {
        const size_t off = (size_t)bid * 2048 + (size_t)tid * 8;
        float4 f0 = *(const float4*)(x + off);
        float4 f1 = *(const float4*)(x + off + 4);
        bf16x8 o;
        o[0] = (short)f2bf(f0.x); o[1] = (short)f2bf(f0.y);
        o[2] = (short)f2bf(f0.z); o[3] = (short)f2bf(f0.w);
        o[4] = (short)f2bf(f1.x); o[5] = (short)f2bf(f1.y);
        o[6] = (short)f2bf(f1.z); o[7] = (short)f2bf(f1.w);
        *(bf16x8*)(xb + off) = o;
    } else if (bid < 1120) {
        const size_t off = (size_t)(bid - 1024) * 2048 + (size_t)tid * 8;
        const float* src = (off < 65536) ? wq : ((off < 131072) ? wk : wv);
        const size_t loc = off & 65535;
        float4 f0 = *(const float4*)(src + loc);
        float4 f1 = *(const float4*)(src + loc + 4);
        bf16x8 o;
        o[0] = (short)f2bf(f0.x); o[1] = (short)f2bf(f0.y);
        o[2] = (short)f2bf(f0.z); o[3] = (short)f2bf(f0.w);
        o[4] = (short)f2bf(f1.x); o[5] = (short)f2bf(f1.y);
        o[6] = (short)f2bf(f1.z); o[7] = (short)f2bf(f1.w);
        *(bf16x8*)(wb + off) = o;
    } else {
        QbG[tid] = 0; QbG[(size_t)8193 * 256 + tid] = 0;
        VbG[tid] = 0; VbG[(size_t)8193 * 256 + tid] = 0;
    }
}

// ---------------------------------------------------------------------------
// qkv via MFMA: sel = blockIdx.y (0=q,1=k,2=v); block does 64 rows x 256 cols,
// 4 waves each own 64 cols. Epilogue: +bias, bf16 store, sumsq (q,k) or
// column-sum (v) side reductions.
// ---------------------------------------------------------------------------
__global__ void __launch_bounds__(256)
qkv_mfma(const ushort_t* __restrict__ xb, const ushort_t* __restrict__ wb,
         const float* __restrict__ bq, const float* __restrict__ bk,
         const float* __restrict__ bv,
         ushort_t* __restrict__ QbG, ushort_t* __restrict__ Kb,
         ushort_t* __restrict__ VbG,
         float* __restrict__ RED, float* __restrict__ SVP)
{
    __shared__ float lds4[4];
    const int tid = threadIdx.x, lane = tid & 63, wid = tid >> 6;
    const int sel = blockIdx.y;
    const int i0 = blockIdx.x * 64;
    const int jw = wid * 64;
    const int l15 = lane & 15, kg = lane >> 4;
    const ushort_t* W = wb + (size_t)sel * 65536;
    const float* B = (sel == 0) ? bq : ((sel == 1) ? bk : bv);
    ushort_t* dst = (sel == 0) ? (QbG + 256) : ((sel == 1) ? Kb : (VbG + 256));

    f32x4 acc[4][4];
#pragma unroll
    for (int mi = 0; mi < 4; ++mi)
#pragma unroll
        for (int ni = 0; ni < 4; ++ni) acc[mi][ni] = 0.0f;

    for (int k0 = 0; k0 < 256; k0 += 32) {
        bf16x8 a[4], b[4];
#pragma unroll
        for (int mi = 0; mi < 4; ++mi)
            a[mi] = *(const bf16x8*)(xb + (size_t)(i0 + 16 * mi + l15) * 256 + k0 + 8 * kg);
#pragma unroll
        for (int ni = 0; ni < 4; ++ni)
            b[ni] = *(const bf16x8*)(W + (size_t)(jw + 16 * ni + l15) * 256 + k0 + 8 * kg);
#pragma unroll
        for (int mi = 0; mi < 4; ++mi)
#pragma unroll
            for (int ni = 0; ni < 4; ++ni)
                acc[mi][ni] = __builtin_amdgcn_mfma_f32_16x16x32_bf16(a[mi], b[ni], acc[mi][ni], 0, 0, 0);
    }

    float ssq = 0.0f;
    float colp[4] = {0.0f, 0.0f, 0.0f, 0.0f};
#pragma unroll
    for (int mi = 0; mi < 4; ++mi)
#pragma unroll
        for (int ni = 0; ni < 4; ++ni) {
            const int col = jw + 16 * ni + l15;
            const float bias = B[col];
#pragma unroll
            for (int r = 0; r < 4; ++r) {
                const int row = i0 + 16 * mi + 4 * kg + r;
                float val = acc[mi][ni][r] + bias;
                dst[(size_t)row * 256 + col] = f2bf(val);
                ssq = fmaf(val, val, ssq);
                colp[ni] += val;
            }
        }

    if (sel < 2) {
        float s = ssq;
#pragma unroll
        for (int o = 32; o > 0; o >>= 1) s += __shfl_down(s, o);
        if (lane == 0) lds4[wid] = s;
        __syncthreads();
        if (tid == 0)
            RED[sel * 128 + blockIdx.x] = lds4[0] + lds4[1] + lds4[2] + lds4[3];
    } else {
        // column sums over this block's 64 rows: reduce across kg groups
#pragma unroll
        for (int ni = 0; ni < 4; ++ni) {
            float v = colp[ni];
            v += __shfl_xor(v, 16);
            v += __shfl_xor(v, 32);
            if (kg == 0)
                SVP[(size_t)blockIdx.x * 256 + jw + 16 * ni + l15] = v;
        }
    }
}

// ---------------------------------------------------------------------------
// KTb[d][t] = Kb[t][d]  (bf16 32x32 LDS transpose)
// ---------------------------------------------------------------------------
__global__ void transpose_k(const ushort_t* __restrict__ Kb, ushort_t* __restrict__ KT)
{
    __shared__ ushort_t tile[32][33];
    const int tid = threadIdx.x;
    const int t0 = blockIdx.x * 32, d0 = blockIdx.y * 32;
#pragma unroll
    for (int p = 0; p < 4; ++p) {
        int idx = tid + p * 256;
        int r = idx >> 5, c = idx & 31;
        tile[r][c] = Kb[(size_t)(t0 + r) * 256 + d0 + c];
    }
    __syncthreads();
#pragma unroll
    for (int p = 0; p < 4; ++p) {
        int idx = tid + p * 256;
        int r = idx >> 5, c = idx & 31;
        KT[(size_t)(d0 + r) * 8192 + t0 + c] = tile[c][r];
    }
}

// ---------------------------------------------------------------------------
// scale = 1/(||q|| ||k||);  SVC[j] = cb * sum_t V[t][j]
// ---------------------------------------------------------------------------
__global__ void finish_scale_sv(const float* __restrict__ RED,
                                const float* __restrict__ SVP,
                                const float* __restrict__ cb,
                                float* __restrict__ SC, float* __restrict__ SVC)
{
    __shared__ float lds[8];
    const int t = threadIdx.x;
    float sq = (t < 128) ? RED[t] : 0.0f;
    float sk = (t < 128) ? RED[128 + t] : 0.0f;
#pragma unroll
    for (int o = 32; o > 0; o >>= 1) { sq += __shfl_down(sq, o); sk += __shfl_down(sk, o); }
    if ((t & 63) == 0) { lds[t >> 6] = sq; lds[4 + (t >> 6)] = sk; }
    __syncthreads();
    if (t == 0) {
        float SQ = lds[0] + lds[1] + lds[2] + lds[3];
        float SK = lds[4] + lds[5] + lds[6] + lds[7];
        SC[0] = rsqrtf(SQ) * rsqrtf(SK);
    }
    float s = 0.0f;
    for (int bx = 0; bx < 128; ++bx) s += SVP[(size_t)bx * 256 + t];
    SVC[t] = cb[0] * s;
}

// ---------------------------------------------------------------------------
// G_v[d][j] = sum_t K[t][d] * V[t+1-v][j]   (v-shift on V via guard rows)
// grid (2, 2, 24): z = ks*3+v, ks in 0..7 (t-chunks of 1024). MFMA 16x16x32.
// ---------------------------------------------------------------------------
__global__ void __launch_bounds__(256)
g_mfma(const ushort_t* __restrict__ KT, const ushort_t* __restrict__ VbG,
       float* __restrict__ Gpart)
{
    const int tid = threadIdx.x, lane = tid & 63, wid = tid >> 6;
    const int wr = wid >> 1, wc = wid & 1;
    const int d0 = blockIdx.x * 128 + wr * 64;
    const int j0 = blockIdx.y * 128 + wc * 64;
    const int z = blockIdx.z, ks = z / 3, v = z - ks * 3;
    const int tbase = ks * 1024;
    const int l15 = lane & 15, kg = lane >> 4;

    f32x4 acc[4][4];
#pragma unroll
    for (int mi = 0; mi < 4; ++mi)
#pragma unroll
        for (int ni = 0; ni < 4; ++ni) acc[mi][ni] = 0.0f;

    for (int tt = 0; tt < 1024; tt += 32) {
        const int t0 = tbase + tt;
        bf16x8 a[4];
#pragma unroll
        for (int mi = 0; mi < 4; ++mi)
            a[mi] = *(const bf16x8*)(KT + (size_t)(d0 + 16 * mi + l15) * 8192 + t0 + 8 * kg);
#pragma unroll
        for (int ni = 0; ni < 4; ++ni) {
            bf16x8 b;
            const ushort_t* vp = VbG + (size_t)(t0 + 8 * kg + 2 - v) * 256
                                     + (j0 + 16 * ni + l15);
#pragma unroll
            for (int e = 0; e < 8; ++e) b[e] = (short)vp[(size_t)e * 256];
#pragma unroll
            for (int mi = 0; mi < 4; ++mi)
                acc[mi][ni] = __builtin_amdgcn_mfma_f32_16x16x32_bf16(a[mi], b, acc[mi][ni], 0, 0, 0);
        }
    }

    float* gp = Gpart + (size_t)z * 65536;
#pragma unroll
    for (int mi = 0; mi < 4; ++mi)
#pragma unroll
        for (int ni = 0; ni < 4; ++ni)
#pragma unroll
            for (int r = 0; r < 4; ++r)
                gp[(size_t)(d0 + 16 * mi + 4 * kg + r) * 256 + (j0 + 16 * ni + l15)]
                    = acc[mi][ni][r];
}

// ---------------------------------------------------------------------------
// MTb[u][j][d] = scale * sum_v cw[u][v] * (sum_ks Gpart[ks*3+v][d][j])  (bf16)
// ---------------------------------------------------------------------------
__global__ void combine_m(const float* __restrict__ Gpart, const float* __restrict__ cw,
                          const float* __restrict__ SC, ushort_t* __restrict__ MT)
{
    const int d = blockIdx.x, j = threadIdx.x;
    float g[3] = {0.0f, 0.0f, 0.0f};
    for (int ks = 0; ks < 8; ++ks)
#pragma unroll
        for (int v = 0; v < 3; ++v)
            g[v] += Gpart[(size_t)(ks * 3 + v) * 65536 + (size_t)d * 256 + j];
    const float sc = SC[0];
#pragma unroll
    for (int u = 0; u < 3; ++u) {
        float m = sc * (cw[u * 3 + 0] * g[0] + cw[u * 3 + 1] * g[1] + cw[u * 3 + 2] * g[2]);
        MT[(size_t)u * 65536 + (size_t)j * 256 + d] = f2bf(m);
    }
}

// ---------------------------------------------------------------------------
// attn[i][j] = sum_u sum_d Q[i+u-1][d] MT_u[j][d]  + SVC[j]
// ---------------------------------------------------------------------------
__global__ void __launch_bounds__(256)
attn_mfma(const ushort_t* __restrict__ QbG, const ushort_t* __restrict__ MT,
          const float* __restrict__ SVC, float* __restrict__ attn)
{
    const int tid = threadIdx.x, lane = tid & 63, wid = tid >> 6;
    const int i0 = blockIdx.x * 64;
    const int jw = blockIdx.y * 128 + wid * 32;
    const int l15 = lane & 15, kg = lane >> 4;

    f32x4 acc[4][2];
#pragma unroll
    for (int mi = 0; mi < 4; ++mi) { acc[mi][0] = 0.0f; acc[mi][1] = 0.0f; }

    for (int k0 = 0; k0 < 256; k0 += 32) {
        bf16x8 a[3][4], b[3][2];
#pragma unroll
        for (int u = 0; u < 3; ++u)
#pragma unroll
            for (int mi = 0; mi < 4; ++mi)
                a[u][mi] = *(const bf16x8*)(QbG
                    + (size_t)(i0 + 16 * mi + l15 + u) * 256 + k0 + 8 * kg);
#pragma unroll
        for (int u = 0; u < 3; ++u)
#pragma unroll
            for (int ni = 0; ni < 2; ++ni)
                b[u][ni] = *(const bf16x8*)(MT + (size_t)u * 65536
                    + (size_t)(jw + 16 * ni + l15) * 256 + k0 + 8 * kg);
#pragma unroll
        for (int mi = 0; mi < 4; ++mi)
#pragma unroll
            for (int ni = 0; ni < 2; ++ni)
#pragma unroll
                for (int u = 0; u < 3; ++u)
                    acc[mi][ni] = __builtin_amdgcn_mfma_f32_16x16x32_bf16(
                        a[u][mi], b[u][ni], acc[mi][ni], 0, 0, 0);
    }

    float sv[2];
    sv[0] = SVC[jw + l15];
    sv[1] = SVC[jw + 16 + l15];
#pragma unroll
    for (int mi = 0; mi < 4; ++mi)
#pragma unroll
        for (int ni = 0; ni < 2; ++ni)
#pragma unroll
            for (int r = 0; r < 4; ++r)
                attn[(size_t)(i0 + 16 * mi + 4 * kg + r) * 256 + (jw + 16 * ni + l15)]
                    = acc[mi][ni][r] + sv[ni];
}

// ---------------------------------------------------------------------------
// h = x + LN1(attn) (in-place in d_out); l2 = LN2(h).
// Wave-per-row: 4 rows/block, float4 per lane, shuffle-only reductions.
// ---------------------------------------------------------------------------
__device__ __forceinline__ float waveSum(float v)
{
#pragma unroll
    for (int o = 32; o > 0; o >>= 1) v += __shfl_xor(v, o);
    return v;
}

__global__ void ln_fuse(const float* __restrict__ x, const float* attn,
                        const float* __restrict__ ln1g, const float* __restrict__ ln1b,
                        const float* __restrict__ ln2g, const float* __restrict__ ln2b,
                        float* h, float* __restrict__ l2)
{
    const int lane = threadIdx.x & 63, wid = threadIdx.x >> 6;
    const size_t row = (size_t)blockIdx.x * 4 + wid;
    const size_t off = row * 256 + lane * 4;

    float4 a4 = *(const float4*)(attn + off);
    float m = waveSum(a4.x + a4.y + a4.z + a4.w) * (1.0f / D_);
    float4 d4 = make_float4(a4.x - m, a4.y - m, a4.z - m, a4.w - m);
    float var = waveSum(d4.x * d4.x + d4.y * d4.y + d4.z * d4.z + d4.w * d4.w) * (1.0f / D_);
    float rs = rsqrtf(var + EPSF);

    float4 x4 = *(const float4*)(x + off);
    float4 g4 = *(const float4*)(ln1g + lane * 4);
    float4 b4 = *(const float4*)(ln1b + lane * 4);
    float4 h4;
    h4.x = x4.x + d4.x * rs * g4.x + b4.x;
    h4.y = x4.y + d4.y * rs * g4.y + b4.y;
    h4.z = x4.z + d4.z * rs * g4.z + b4.z;
    h4.w = x4.w + d4.w * rs * g4.w + b4.w;
    *(float4*)(h + off) = h4;

    float m2 = waveSum(h4.x + h4.y + h4.z + h4.w) * (1.0f / D_);
    float4 e4 = make_float4(h4.x - m2, h4.y - m2, h4.z - m2, h4.w - m2);
    float v2 = waveSum(e4.x * e4.x + e4.y * e4.y + e4.z * e4.z + e4.w * e4.w) * (1.0f / D_);
    float rs2 = rsqrtf(v2 + EPSF);

    float4 g24 = *(const float4*)(ln2g + lane * 4);
    float4 b24 = *(const float4*)(ln2b + lane * 4);
    float4 o4;
    o4.x = e4.x * rs2 * g24.x + b24.x;
    o4.y = e4.y * rs2 * g24.y + b24.y;
    o4.z = e4.z * rs2 * g24.z + b24.z;
    o4.w = e4.w * rs2 * g24.w + b24.w;
    *(float4*)(l2 + off) = o4;
}

// ---------------------------------------------------------------------------
// z = l2 @ m1w^T : 32x128 tiles, grid (256,1)
// ---------------------------------------------------------------------------
__global__ void __launch_bounds__(256, 2)
gemm_z32(const float* __restrict__ X, const float* __restrict__ W, float* __restrict__ C)
{
    __shared__ float XsT[32][36];
    __shared__ float WsT[32][132];
    const int tid = threadIdx.x;
    const int i0 = blockIdx.x * 32;
    const int tr = tid >> 4, tc = tid & 15;
    float acc[2][8] = {};
    for (int k0 = 0; k0 < 256; k0 += 32) {
        __syncthreads();
#pragma unroll
        for (int p = 0; p < 4; ++p) {
            int idx = tid + p * 256;
            int r = idx >> 5, c = idx & 31;
            XsT[c][r] = X[(size_t)(i0 + r) * 256 + k0 + c];
        }
#pragma unroll
        for (int p = 0; p < 16; ++p) {
            int idx = tid + p * 256;
            int r = idx >> 5, c = idx & 31;
            WsT[c][r] = W[(size_t)r * 256 + k0 + c];
        }
        __syncthreads();
#pragma unroll
        for (int kk = 0; kk < 32; ++kk) {
            float a0 = XsT[kk][tr * 2], a1 = XsT[kk][tr * 2 + 1];
            float b[8];
            *(float4*)&b[0] = *(const float4*)&WsT[kk][tc * 8];
            *(float4*)&b[4] = *(const float4*)&WsT[kk][tc * 8 + 4];
#pragma unroll
            for (int w2 = 0; w2 < 8; ++w2) {
                acc[0][w2] = fmaf(a0, b[w2], acc[0][w2]);
                acc[1][w2] = fmaf(a1, b[w2], acc[1][w2]);
            }
        }
    }
#pragma unroll
    for (int u = 0; u < 2; ++u)
#pragma unroll
        for (int w2 = 0; w2 < 8; ++w2)
            C[(size_t)(i0 + tr * 2 + u) * 128 + tc * 8 + w2] = acc[u][w2];
}

// ---------------------------------------------------------------------------
// BN stats, two-stage coalesced.
// ---------------------------------------------------------------------------
__global__ void bn_part(const float* __restrict__ z, float* __restrict__ BSP)
{
    __shared__ float ls[2][128], lq[2][128];
    const int c = threadIdx.x & 127, rr = threadIdx.x >> 7;
    const int r0 = blockIdx.x * 128;
    float s = 0.0f, sq = 0.0f;
    for (int r = r0 + rr; r < r0 + 128; r += 2) {
        float v = z[(size_t)r * 128 + c];
        s += v; sq = fmaf(v, v, sq);
    }
    ls[rr][c] = s; lq[rr][c] = sq;
    __syncthreads();
    if (threadIdx.x < 128) {
        BSP[(size_t)blockIdx.x * 256 + threadIdx.x]       = ls[0][threadIdx.x] + ls[1][threadIdx.x];
        BSP[(size_t)blockIdx.x * 256 + 128 + threadIdx.x] = lq[0][threadIdx.x] + lq[1][threadIdx.x];
    }
}

__global__ void bn_finish(const float* __restrict__ BSP,
                          const float* __restrict__ bng, const float* __restrict__ bnb,
                          float* __restrict__ bn_a, float* __restrict__ bn_b)
{
    const int c = threadIdx.x;   // 128 threads
    float s = 0.0f, sq = 0.0f;
    for (int b = 0; b < 64; ++b) {
        s  += BSP[(size_t)b * 256 + c];
        sq += BSP[(size_t)b * 256 + 128 + c];
    }
    float mu = s * (1.0f / N_);
    float var = sq * (1.0f / N_) - mu * mu;
    float aa = rsqrtf(var + EPSF) * bng[c];
    bn_a[c] = aa;
    bn_b[c] = bnb[c] - mu * aa;
}

// ---------------------------------------------------------------------------
// out = h + relu(z*a+b) @ m2w^T : 32x128 tiles, grid (256,2), in-place d_out
// ---------------------------------------------------------------------------
__global__ void __launch_bounds__(256, 2)
gemm_out32(const float* __restrict__ Z, const float* __restrict__ W,
           const float* __restrict__ bn_a, const float* __restrict__ bn_b,
           const float* Hbuf, float* out)
{
    __shared__ float XsT[32][36];
    __shared__ float WsT[32][132];
    const int tid = threadIdx.x;
    const int i0 = blockIdx.x * 32;
    const int j0 = blockIdx.y * 128;
    const int tr = tid >> 4, tc = tid & 15;
    float acc[2][8] = {};
    for (int k0 = 0; k0 < 128; k0 += 32) {
        __syncthreads();
#pragma unroll
        for (int p = 0; p < 4; ++p) {
            int idx = tid + p * 256;
            int r = idx >> 5, c = idx & 31;
            float zv = Z[(size_t)(i0 + r) * 128 + k0 + c];
            XsT[c][r] = fmaxf(fmaf(zv, bn_a[k0 + c], bn_b[k0 + c]), 0.0f);
        }
#pragma unroll
        for (int p = 0; p < 16; ++p) {
            int idx = tid + p * 256;
            int r = idx >> 5, c = idx & 31;
            WsT[c][r] = W[(size_t)(j0 + r) * 128 + k0 + c];
        }
        __syncthreads();
#pragma unroll
        for (int kk = 0; kk < 32; ++kk) {
            float a0 = XsT[kk][tr * 2], a1 = XsT[kk][tr * 2 + 1];
            float b[8];
            *(float4*)&b[0] = *(const float4*)&WsT[kk][tc * 8];
            *(float4*)&b[4] = *(const float4*)&WsT[kk][tc * 8 + 4];
#pragma unroll
            for (int w2 = 0; w2 < 8; ++w2) {
                acc[0][w2] = fmaf(a0, b[w2], acc[0][w2]);
                acc[1][w2] = fmaf(a1, b[w2], acc[1][w2]);
            }
        }
    }
#pragma unroll
    for (int u = 0; u < 2; ++u) {
        const size_t i = (size_t)(i0 + tr * 2 + u);
#pragma unroll
        for (int w2 = 0; w2 < 8; ++w2) {
            const size_t idx = i * 256 + j0 + tc * 8 + w2;
            out[idx] = Hbuf[idx] + acc[u][w2];
        }
    }
}

// ---------------------------------------------------------------------------
extern "C" void kernel_launch(void* const* d_in, const int* in_sizes, int n_in,
                              void* d_out, int out_size, void* d_ws, size_t ws_size,
                              hipStream_t stream)
{
    const float* x    = (const float*)d_in[0];
    const float* wq   = (const float*)d_in[1];
    const float* bq   = (const float*)d_in[2];
    const float* wk   = (const float*)d_in[3];
    const float* bk   = (const float*)d_in[4];
    const float* wv   = (const float*)d_in[5];
    const float* bv   = (const float*)d_in[6];
    const float* cw   = (const float*)d_in[7];
    const float* cb   = (const float*)d_in[8];
    const float* m1w  = (const float*)d_in[9];
    const float* m2w  = (const float*)d_in[10];
    const float* bng  = (const float*)d_in[11];
    const float* bnb  = (const float*)d_in[12];
    const float* ln1g = (const float*)d_in[13];
    const float* ln1b = (const float*)d_in[14];
    const float* ln2g = (const float*)d_in[15];
    const float* ln2b = (const float*)d_in[16];

    float* outF = (float*)d_out;
    char*  wsb  = (char*)d_ws;
    if (ws_size < WS_NEED) return;

    ushort_t* QbG = (ushort_t*)(wsb + OFF_QB);
    ushort_t* Kb  = (ushort_t*)(wsb + OFF_KB);
    ushort_t* KT  = (ushort_t*)(wsb + OFF_KT);
    ushort_t* VbG = (ushort_t*)(wsb + OFF_VB);
    float*    GP  = (float*)(wsb + OFF_GP);
    ushort_t* MT  = (ushort_t*)(wsb + OFF_MT);
    float*    SVP = (float*)(wsb + OFF_SVP);
    float*    SVC = (float*)(wsb + OFF_SVC);
    float*    RED = (float*)(wsb + OFF_RED);
    float*    SC  = (float*)(wsb + OFF_SC);
    float*    BNA = (float*)(wsb + OFF_BNA);
    float*    BNB = (float*)(wsb + OFF_BNB);
    ushort_t* WB  = (ushort_t*)(wsb + OFF_WB);
    float*    BSP = (float*)(wsb + OFF_BSP);
    ushort_t* XB  = (ushort_t*)(wsb + OFF_GP);   // alias: dead before g_mfma
    float*    L2  = (float*)(wsb + OFF_KB);      // alias over Kb+KT (dead)
    float*    Z   = (float*)(wsb + OFF_GP);      // alias over GP (dead)

    const dim3 b256(256);

    prep<<<1121, b256, 0, stream>>>(x, wq, wk, wv, XB, WB, QbG, VbG);
    qkv_mfma<<<dim3(128, 3), b256, 0, stream>>>(XB, WB, bq, bk, bv,
                                                QbG, Kb, VbG, RED, SVP);
    transpose_k<<<dim3(256, 8), b256, 0, stream>>>(Kb, KT);
    finish_scale_sv<<<1, b256, 0, stream>>>(RED, SVP, cb, SC, SVC);
    g_mfma<<<dim3(2, 2, 24), b256, 0, stream>>>(KT, VbG, GP);
    combine_m<<<256, b256, 0, stream>>>(GP, cw, SC, MT);
    attn_mfma<<<dim3(128, 2), b256, 0, stream>>>(QbG, MT, SVC, outF);
    ln_fuse<<<2048, b256, 0, stream>>>(x, outF, ln1g, ln1b, ln2g, ln2b, outF, L2);
    gemm_z32<<<dim3(256, 1), b256, 0, stream>>>(L2, m1w, Z);
    bn_part<<<64, b256, 0, stream>>>(Z, BSP);
    bn_finish<<<1, dim3(128), 0, stream>>>(BSP, bng, bnb, BNA, BNB);
    gemm_out32<<<dim3(256, 2), b256, 0, stream>>>(Z, m2w, BNA, BNB, outF, outF);
}

// Round 7
// 145.151 us; speedup vs baseline: 19.6572x; 1.0664x over previous
//
#include <hip/hip_runtime.h>
#include <hip/hip_bf16.h>
#include <math.h>

// ---------------------------------------------------------------------------
// GraphBased_selfAttnLayer — collapsed attention path, 7 launches.
//
//   G_v  = (S_{v-1} K)^T V            (MFMA, K-dim 8192, VT-layout + alignbit)
//   M_u  = scale * sum_v cw[u][v] G_v
//   attn = sum_u S_{u-1}(Q M_u) + cb*colsum(V)
//   h = x + LN1(attn); l2 = LN2(h); z = l2@m1w^T; BN; out = h + relu@m2w^T
//
// Launches: qkv(f32->bf16 in-reg, writes Q,KT,VT + side reductions) -> g ->
//           combine(+scale+SVC) -> attn -> ln -> z(+BN partials) -> out(+BN).
//
// ws (bytes):
//   QbG bf16 [8194][256]   @ 0            (guard rows; aliased later by L2)
//   KT  bf16 [256][8192]   @  4,195,328   (aliased later by L2)
//   VT  bf16 [256][8200]   @  8,389,632   (guard cols 0/8193; VT[j][c]=V[c-1][j])
//   GP  f32 [48][256][256] @ 12,588,032   (aliased later by Z)
//   MT  bf16 [3][256][256] @ 25,170,944
//   SVP f32 [128][256]     @ 25,564,160
//   SVC f32 [256]          @ 25,695,232
//   RED f32 [256]          @ 25,696,256
//   ZSP f32 [128][2][128]  @ 25,697,280   (ends 25,828,352)
// ---------------------------------------------------------------------------

#define N_ 8192
#define D_ 256
#define H_ 128
#define EPSF 1e-5f

typedef unsigned short ushort_t;
typedef unsigned int uint_t;
typedef __attribute__((ext_vector_type(8))) short bf16x8;
typedef __attribute__((ext_vector_type(4))) short bf16x4;
typedef __attribute__((ext_vector_type(4))) float f32x4;

static const size_t OFF_QB  = 0;
static const size_t OFF_KT  = 4195328;
static const size_t OFF_VT  = 8389632;
static const size_t OFF_GP  = 12588032;
static const size_t OFF_MT  = 25170944;
static const size_t OFF_SVP = 25564160;
static const size_t OFF_SVC = 25695232;
static const size_t OFF_RED = 25696256;
static const size_t OFF_ZSP = 25697280;
static const size_t WS_NEED = 25828352;
// aliases: L2 f32 [8192][256] @0 (QbG+KT dead); Z f32 [8192][128] @OFF_GP.

#define VT_S 8200   // VT row stride (elems); 8200*2 % 16 == 0

__device__ __forceinline__ ushort_t f2bf(float f) {
    __hip_bfloat16 h = __float2bfloat16(f);
    return reinterpret_cast<ushort_t&>(h);
}

__device__ __forceinline__ bf16x8 cvt8(float4 f0, float4 f1) {
    bf16x8 o;
    o[0] = (short)f2bf(f0.x); o[1] = (short)f2bf(f0.y);
    o[2] = (short)f2bf(f0.z); o[3] = (short)f2bf(f0.w);
    o[4] = (short)f2bf(f1.x); o[5] = (short)f2bf(f1.y);
    o[6] = (short)f2bf(f1.z); o[7] = (short)f2bf(f1.w);
    return o;
}

// ---------------------------------------------------------------------------
// qkv via MFMA, f32 inputs converted in-register. grid (128, 3).
// Block: 64 rows x 256 cols, 4 waves each 64 cols.
// Epilogues: Q -> QbG row-major (+1 row guard); K -> KT[d][t] scatter (bf16x4);
// V -> VT[j][t+1] scatter (split stores); sumsq (q,k) -> RED; colsum (v) -> SVP.
// ---------------------------------------------------------------------------
__global__ void __launch_bounds__(256)
qkv_mfma(const float* __restrict__ x,
         const float* __restrict__ wq, const float* __restrict__ bq,
         const float* __restrict__ wk, const float* __restrict__ bk,
         const float* __restrict__ wv, const float* __restrict__ bv,
         ushort_t* __restrict__ QbG, ushort_t* __restrict__ KT,
         ushort_t* __restrict__ VT,
         float* __restrict__ RED, float* __restrict__ SVP)
{
    __shared__ float lds4[4];
    const int tid = threadIdx.x, lane = tid & 63, wid = tid >> 6;
    const int sel = blockIdx.y;
    const int i0 = blockIdx.x * 64;
    const int jw = wid * 64;
    const int l15 = lane & 15, kg = lane >> 4;
    const float* W = (sel == 0) ? wq : ((sel == 1) ? wk : wv);
    const float* B = (sel == 0) ? bq : ((sel == 1) ? bk : bv);

    // guard rows/cols (block (0,0) only; disjoint from data writes)
    if (sel == 0 && blockIdx.x == 0) {
        QbG[tid] = 0; QbG[(size_t)8193 * 256 + tid] = 0;
        VT[(size_t)tid * VT_S] = 0; VT[(size_t)tid * VT_S + 8193] = 0;
    }

    f32x4 acc[4][4];
#pragma unroll
    for (int mi = 0; mi < 4; ++mi)
#pragma unroll
        for (int ni = 0; ni < 4; ++ni) acc[mi][ni] = 0.0f;

    for (int k0 = 0; k0 < 256; k0 += 32) {
        bf16x8 a[4], b[4];
#pragma unroll
        for (int mi = 0; mi < 4; ++mi) {
            const float* p = x + (size_t)(i0 + 16 * mi + l15) * 256 + k0 + 8 * kg;
            a[mi] = cvt8(*(const float4*)p, *(const float4*)(p + 4));
        }
#pragma unroll
        for (int ni = 0; ni < 4; ++ni) {
            const float* p = W + (size_t)(jw + 16 * ni + l15) * 256 + k0 + 8 * kg;
            b[ni] = cvt8(*(const float4*)p, *(const float4*)(p + 4));
        }
#pragma unroll
        for (int mi = 0; mi < 4; ++mi)
#pragma unroll
            for (int ni = 0; ni < 4; ++ni)
                acc[mi][ni] = __builtin_amdgcn_mfma_f32_16x16x32_bf16(a[mi], b[ni], acc[mi][ni], 0, 0, 0);
    }

    float ssq = 0.0f;
    float colp[4] = {0.0f, 0.0f, 0.0f, 0.0f};

    if (sel == 0) {
#pragma unroll
        for (int mi = 0; mi < 4; ++mi)
#pragma unroll
            for (int ni = 0; ni < 4; ++ni) {
                const int col = jw + 16 * ni + l15;
                const float bias = B[col];
#pragma unroll
                for (int r = 0; r < 4; ++r) {
                    const int row = i0 + 16 * mi + 4 * kg + r;
                    float val = acc[mi][ni][r] + bias;
                    QbG[(size_t)(row + 1) * 256 + col] = f2bf(val);
                    ssq = fmaf(val, val, ssq);
                }
            }
    } else if (sel == 1) {
#pragma unroll
        for (int mi = 0; mi < 4; ++mi)
#pragma unroll
            for (int ni = 0; ni < 4; ++ni) {
                const int col = jw + 16 * ni + l15;   // d
                const float bias = B[col];
                const int tb = i0 + 16 * mi + 4 * kg; // t base (mult of 4)
                bf16x4 pk;
#pragma unroll
                for (int r = 0; r < 4; ++r) {
                    float val = acc[mi][ni][r] + bias;
                    ssq = fmaf(val, val, ssq);
                    pk[r] = (short)f2bf(val);
                }
                *(bf16x4*)(KT + (size_t)col * 8192 + tb) = pk;
            }
    } else {
#pragma unroll
        for (int mi = 0; mi < 4; ++mi)
#pragma unroll
            for (int ni = 0; ni < 4; ++ni) {
                const int col = jw + 16 * ni + l15;   // j
                const float bias = B[col];
                const int tb = i0 + 16 * mi + 4 * kg;
                float v0 = acc[mi][ni][0] + bias, v1 = acc[mi][ni][1] + bias;
                float v2 = acc[mi][ni][2] + bias, v3 = acc[mi][ni][3] + bias;
                colp[ni] += v0 + v1 + v2 + v3;
                ushort_t* p = VT + (size_t)col * VT_S + tb + 1;
                p[0] = f2bf(v0);
                *(uint_t*)(p + 1) = (uint_t)f2bf(v1) | ((uint_t)f2bf(v2) << 16);
                p[3] = f2bf(v3);
            }
    }

    if (sel < 2) {
        float s = ssq;
#pragma unroll
        for (int o = 32; o > 0; o >>= 1) s += __shfl_down(s, o);
        if (lane == 0) lds4[wid] = s;
        __syncthreads();
        if (tid == 0)
            RED[sel * 128 + blockIdx.x] = lds4[0] + lds4[1] + lds4[2] + lds4[3];
    } else {
#pragma unroll
        for (int ni = 0; ni < 4; ++ni) {
            float v = colp[ni];
            v += __shfl_xor(v, 16);
            v += __shfl_xor(v, 32);
            if (kg == 0)
                SVP[(size_t)blockIdx.x * 256 + jw + 16 * ni + l15] = v;
        }
    }
}

// ---------------------------------------------------------------------------
// G_v[d][j] = sum_t K[t][d] * V[t+1-v][j].  grid (4, 2, 16) = 128 blocks.
// Block: 64d x 128j, 4 waves each 64d x 32j, t-range 512 per ks.
// B-frags: 2 aligned dwordx4 loads give v=2 (r0) and v=0 (r2); v=1 built
// register-only: (r0>>16)|(r2<<16).
// ---------------------------------------------------------------------------
__global__ void __launch_bounds__(256)
g_mfma(const ushort_t* __restrict__ KT, const ushort_t* __restrict__ VT,
       float* __restrict__ GP)
{
    const int tid = threadIdx.x, lane = tid & 63, wid = tid >> 6;
    const int d0 = blockIdx.x * 64;
    const int jw = blockIdx.y * 128 + wid * 32;
    const int ks = blockIdx.z;
    const int l15 = lane & 15, kg = lane >> 4;

    f32x4 acc[3][4][2];
#pragma unroll
    for (int v = 0; v < 3; ++v)
#pragma unroll
        for (int mi = 0; mi < 4; ++mi) { acc[v][mi][0] = 0.0f; acc[v][mi][1] = 0.0f; }

    for (int tt = 0; tt < 512; tt += 32) {
        const int t0 = ks * 512 + tt;
        bf16x8 a[4];
#pragma unroll
        for (int mi = 0; mi < 4; ++mi)
            a[mi] = *(const bf16x8*)(KT + (size_t)(d0 + 16 * mi + l15) * 8192 + t0 + 8 * kg);
#pragma unroll
        for (int ni = 0; ni < 2; ++ni) {
            const ushort_t* vp = VT + (size_t)(jw + 16 * ni + l15) * VT_S + t0 + 8 * kg;
            uint4 r0 = *(const uint4*)vp;          // cols +0..7  -> b for v=2
            uint4 r2 = *(const uint4*)(vp + 2);    // cols +2..9  -> b for v=0
            uint4 m1;
            m1.x = (r0.x >> 16) | (r2.x << 16);
            m1.y = (r0.y >> 16) | (r2.y << 16);
            m1.z = (r0.z >> 16) | (r2.z << 16);
            m1.w = (r0.w >> 16) | (r2.w << 16);    // cols +1..8  -> b for v=1
            bf16x8 b2 = __builtin_bit_cast(bf16x8, r0);
            bf16x8 b0 = __builtin_bit_cast(bf16x8, r2);
            bf16x8 b1 = __builtin_bit_cast(bf16x8, m1);
#pragma unroll
            for (int mi = 0; mi < 4; ++mi) {
                acc[0][mi][ni] = __builtin_amdgcn_mfma_f32_16x16x32_bf16(a[mi], b0, acc[0][mi][ni], 0, 0, 0);
                acc[1][mi][ni] = __builtin_amdgcn_mfma_f32_16x16x32_bf16(a[mi], b1, acc[1][mi][ni], 0, 0, 0);
                acc[2][mi][ni] = __builtin_amdgcn_mfma_f32_16x16x32_bf16(a[mi], b2, acc[2][mi][ni], 0, 0, 0);
            }
        }
    }

#pragma unroll
    for (int v = 0; v < 3; ++v) {
        float* gp = GP + (size_t)(ks * 3 + v) * 65536;
#pragma unroll
        for (int mi = 0; mi < 4; ++mi)
#pragma unroll
            for (int ni = 0; ni < 2; ++ni)
#pragma unroll
                for (int r = 0; r < 4; ++r)
                    gp[(size_t)(d0 + 16 * mi + 4 * kg + r) * 256 + (jw + 16 * ni + l15)]
                        = acc[v][mi][ni][r];
    }
}

// ---------------------------------------------------------------------------
// MT[u][j][d] = scale * sum_v cw[u][v] * sum_ks GP[ks*3+v][d][j]  (bf16).
// scale computed redundantly per block from RED; block 0 computes SVC.
// ---------------------------------------------------------------------------
__global__ void combine_m(const float* __restrict__ GP, const float* __restrict__ cw,
                          const float* __restrict__ RED, const float* __restrict__ SVP,
                          const float* __restrict__ cb,
                          ushort_t* __restrict__ MT, float* __restrict__ SVC)
{
    const int d = blockIdx.x, j = threadIdx.x;
    float g[3] = {0.0f, 0.0f, 0.0f};
    for (int ks = 0; ks < 16; ++ks)
#pragma unroll
        for (int v = 0; v < 3; ++v)
            g[v] += GP[(size_t)(ks * 3 + v) * 65536 + (size_t)d * 256 + j];

    float sq = 0.0f, sk = 0.0f;
    for (int i = 0; i < 128; ++i) { sq += RED[i]; sk += RED[128 + i]; }
    const float sc = rsqrtf(sq) * rsqrtf(sk);

#pragma unroll
    for (int u = 0; u < 3; ++u) {
        float m = sc * (cw[u * 3 + 0] * g[0] + cw[u * 3 + 1] * g[1] + cw[u * 3 + 2] * g[2]);
        MT[(size_t)u * 65536 + (size_t)j * 256 + d] = f2bf(m);
    }
    if (d == 0) {
        float s = 0.0f;
        for (int b = 0; b < 128; ++b) s += SVP[(size_t)b * 256 + j];
        SVC[j] = cb[0] * s;
    }
}

// ---------------------------------------------------------------------------
// attn[i][j] = sum_u sum_d Q[i+u-1][d] MT_u[j][d]  + SVC[j]
// ---------------------------------------------------------------------------
__global__ void __launch_bounds__(256)
attn_mfma(const ushort_t* __restrict__ QbG, const ushort_t* __restrict__ MT,
          const float* __restrict__ SVC, float* __restrict__ attn)
{
    const int tid = threadIdx.x, lane = tid & 63, wid = tid >> 6;
    const int i0 = blockIdx.x * 64;
    const int jw = blockIdx.y * 128 + wid * 32;
    const int l15 = lane & 15, kg = lane >> 4;

    f32x4 acc[4][2];
#pragma unroll
    for (int mi = 0; mi < 4; ++mi) { acc[mi][0] = 0.0f; acc[mi][1] = 0.0f; }

    for (int k0 = 0; k0 < 256; k0 += 32) {
        bf16x8 a[3][4], b[3][2];
#pragma unroll
        for (int u = 0; u < 3; ++u)
#pragma unroll
            for (int mi = 0; mi < 4; ++mi)
                a[u][mi] = *(const bf16x8*)(QbG
                    + (size_t)(i0 + 16 * mi + l15 + u) * 256 + k0 + 8 * kg);
#pragma unroll
        for (int u = 0; u < 3; ++u)
#pragma unroll
            for (int ni = 0; ni < 2; ++ni)
                b[u][ni] = *(const bf16x8*)(MT + (size_t)u * 65536
                    + (size_t)(jw + 16 * ni + l15) * 256 + k0 + 8 * kg);
#pragma unroll
        for (int mi = 0; mi < 4; ++mi)
#pragma unroll
            for (int ni = 0; ni < 2; ++ni)
#pragma unroll
                for (int u = 0; u < 3; ++u)
                    acc[mi][ni] = __builtin_amdgcn_mfma_f32_16x16x32_bf16(
                        a[u][mi], b[u][ni], acc[mi][ni], 0, 0, 0);
    }

    float sv[2];
    sv[0] = SVC[jw + l15];
    sv[1] = SVC[jw + 16 + l15];
#pragma unroll
    for (int mi = 0; mi < 4; ++mi)
#pragma unroll
        for (int ni = 0; ni < 2; ++ni)
#pragma unroll
            for (int r = 0; r < 4; ++r)
                attn[(size_t)(i0 + 16 * mi + 4 * kg + r) * 256 + (jw + 16 * ni + l15)]
                    = acc[mi][ni][r] + sv[ni];
}

// ---------------------------------------------------------------------------
// h = x + LN1(attn) (in-place in d_out); l2 = LN2(h). Wave-per-row.
// ---------------------------------------------------------------------------
__device__ __forceinline__ float waveSum(float v)
{
#pragma unroll
    for (int o = 32; o > 0; o >>= 1) v += __shfl_xor(v, o);
    return v;
}

__global__ void ln_fuse(const float* __restrict__ x, const float* attn,
                        const float* __restrict__ ln1g, const float* __restrict__ ln1b,
                        const float* __restrict__ ln2g, const float* __restrict__ ln2b,
                        float* h, float* __restrict__ l2)
{
    const int lane = threadIdx.x & 63, wid = threadIdx.x >> 6;
    const size_t row = (size_t)blockIdx.x * 4 + wid;
    const size_t off = row * 256 + lane * 4;

    float4 a4 = *(const float4*)(attn + off);
    float m = waveSum(a4.x + a4.y + a4.z + a4.w) * (1.0f / D_);
    float4 d4 = make_float4(a4.x - m, a4.y - m, a4.z - m, a4.w - m);
    float var = waveSum(d4.x * d4.x + d4.y * d4.y + d4.z * d4.z + d4.w * d4.w) * (1.0f / D_);
    float rs = rsqrtf(var + EPSF);

    float4 x4 = *(const float4*)(x + off);
    float4 g4 = *(const float4*)(ln1g + lane * 4);
    float4 b4 = *(const float4*)(ln1b + lane * 4);
    float4 h4;
    h4.x = x4.x + d4.x * rs * g4.x + b4.x;
    h4.y = x4.y + d4.y * rs * g4.y + b4.y;
    h4.z = x4.z + d4.z * rs * g4.z + b4.z;
    h4.w = x4.w + d4.w * rs * g4.w + b4.w;
    *(float4*)(h + off) = h4;

    float m2 = waveSum(h4.x + h4.y + h4.z + h4.w) * (1.0f / D_);
    float4 e4 = make_float4(h4.x - m2, h4.y - m2, h4.z - m2, h4.w - m2);
    float v2 = waveSum(e4.x * e4.x + e4.y * e4.y + e4.z * e4.z + e4.w * e4.w) * (1.0f / D_);
    float rs2 = rsqrtf(v2 + EPSF);

    float4 g24 = *(const float4*)(ln2g + lane * 4);
    float4 b24 = *(const float4*)(ln2b + lane * 4);
    float4 o4;
    o4.x = e4.x * rs2 * g24.x + b24.x;
    o4.y = e4.y * rs2 * g24.y + b24.y;
    o4.z = e4.z * rs2 * g24.z + b24.z;
    o4.w = e4.w * rs2 * g24.w + b24.w;
    *(float4*)(l2 + off) = o4;
}

// ---------------------------------------------------------------------------
// z = l2 @ m1w^T, 64x128 tiles (grid 128) + BN column partials -> ZSP.
// ---------------------------------------------------------------------------
__global__ void __launch_bounds__(256, 2)
gemm_z64(const float* __restrict__ X, const float* __restrict__ W,
         float* __restrict__ Z, float* __restrict__ ZSP)
{
    __shared__ float XsT[32][68];
    __shared__ float WsT[32][132];
    __shared__ float sW[4][128], qW[4][128];
    const int tid = threadIdx.x;
    const int i0 = blockIdx.x * 64;
    const int tr = tid >> 4, tc = tid & 15;
    const int lane = tid & 63, wid = tid >> 6;
    float acc[4][8] = {};

    for (int k0 = 0; k0 < 256; k0 += 32) {
        __syncthreads();
#pragma unroll
        for (int p = 0; p < 8; ++p) {
            int idx = tid + p * 256;
            int r = idx >> 5, c = idx & 31;
            XsT[c][r] = X[(size_t)(i0 + r) * 256 + k0 + c];
        }
#pragma unroll
        for (int p = 0; p < 16; ++p) {
            int idx = tid + p * 256;
            int r = idx >> 5, c = idx & 31;
            WsT[c][r] = W[(size_t)r * 256 + k0 + c];
        }
        __syncthreads();
#pragma unroll
        for (int kk = 0; kk < 32; ++kk) {
            float a[4];
#pragma unroll
            for (int u = 0; u < 4; ++u) a[u] = XsT[kk][tr * 4 + u];
            float b[8];
            *(float4*)&b[0] = *(const float4*)&WsT[kk][tc * 8];
            *(float4*)&b[4] = *(const float4*)&WsT[kk][tc * 8 + 4];
#pragma unroll
            for (int u = 0; u < 4; ++u)
#pragma unroll
                for (int w2 = 0; w2 < 8; ++w2)
                    acc[u][w2] = fmaf(a[u], b[w2], acc[u][w2]);
        }
    }

    float s[8] = {}, q[8] = {};
#pragma unroll
    for (int u = 0; u < 4; ++u) {
        const size_t row = (size_t)(i0 + tr * 4 + u);
#pragma unroll
        for (int w2 = 0; w2 < 8; ++w2) {
            float zv = acc[u][w2];
            Z[row * 128 + tc * 8 + w2] = zv;
            s[w2] += zv;
            q[w2] = fmaf(zv, zv, q[w2]);
        }
    }
#pragma unroll
    for (int w2 = 0; w2 < 8; ++w2) {
        s[w2] += __shfl_xor(s[w2], 16); s[w2] += __shfl_xor(s[w2], 32);
        q[w2] += __shfl_xor(q[w2], 16); q[w2] += __shfl_xor(q[w2], 32);
    }
    if (lane < 16) {
#pragma unroll
        for (int w2 = 0; w2 < 8; ++w2) {
            sW[wid][(lane & 15) * 8 + w2] = s[w2];
            qW[wid][(lane & 15) * 8 + w2] = q[w2];
        }
    }
    __syncthreads();
    if (tid < 128) {
        float ss = sW[0][tid] + sW[1][tid] + sW[2][tid] + sW[3][tid];
        float qq = qW[0][tid] + qW[1][tid] + qW[2][tid] + qW[3][tid];
        ZSP[(size_t)blockIdx.x * 256 + tid] = ss;
        ZSP[(size_t)blockIdx.x * 256 + 128 + tid] = qq;
    }
}

// ---------------------------------------------------------------------------
// out = h + relu(z*a+b) @ m2w^T, 32x128 tiles (grid (256,2)); BN affine
// computed in-prologue from ZSP into LDS. In-place over d_out.
// ---------------------------------------------------------------------------
__global__ void __launch_bounds__(256, 2)
gemm_out32(const float* __restrict__ Z, const float* __restrict__ W,
           const float* __restrict__ ZSP,
           const float* __restrict__ bng, const float* __restrict__ bnb,
           float* out)
{
    __shared__ float XsT[32][36];
    __shared__ float WsT[32][132];
    __shared__ float bnA[128], bnB[128];
    const int tid = threadIdx.x;
    const int i0 = blockIdx.x * 32;
    const int j0 = blockIdx.y * 128;
    const int tr = tid >> 4, tc = tid & 15;

    if (tid < 128) {
        float s = 0.0f, q = 0.0f;
        for (int b = 0; b < 128; ++b) {
            s += ZSP[(size_t)b * 256 + tid];
            q += ZSP[(size_t)b * 256 + 128 + tid];
        }
        float mu = s * (1.0f / N_);
        float var = q * (1.0f / N_) - mu * mu;
        float aa = rsqrtf(var + EPSF) * bng[tid];
        bnA[tid] = aa;
        bnB[tid] = bnb[tid] - mu * aa;
    }

    float acc[2][8] = {};
    for (int k0 = 0; k0 < 128; k0 += 32) {
        __syncthreads();
#pragma unroll
        for (int p = 0; p < 4; ++p) {
            int idx = tid + p * 256;
            int r = idx >> 5, c = idx & 31;
            float zv = Z[(size_t)(i0 + r) * 128 + k0 + c];
            XsT[c][r] = fmaxf(fmaf(zv, bnA[k0 + c], bnB[k0 + c]), 0.0f);
        }
#pragma unroll
        for (int p = 0; p < 16; ++p) {
            int idx = tid + p * 256;
            int r = idx >> 5, c = idx & 31;
            WsT[c][r] = W[(size_t)(j0 + r) * 128 + k0 + c];
        }
        __syncthreads();
#pragma unroll
        for (int kk = 0; kk < 32; ++kk) {
            float a0 = XsT[kk][tr * 2], a1 = XsT[kk][tr * 2 + 1];
            float b[8];
            *(float4*)&b[0] = *(const float4*)&WsT[kk][tc * 8];
            *(float4*)&b[4] = *(const float4*)&WsT[kk][tc * 8 + 4];
#pragma unroll
            for (int w2 = 0; w2 < 8; ++w2) {
                acc[0][w2] = fmaf(a0, b[w2], acc[0][w2]);
                acc[1][w2] = fmaf(a1, b[w2], acc[1][w2]);
            }
        }
    }
#pragma unroll
    for (int u = 0; u < 2; ++u) {
        const size_t i = (size_t)(i0 + tr * 2 + u);
#pragma unroll
        for (int w2 = 0; w2 < 8; ++w2) {
            const size_t idx = i * 256 + j0 + tc * 8 + w2;
            out[idx] = out[idx] + acc[u][w2];
        }
    }
}

// ---------------------------------------------------------------------------
extern "C" void kernel_launch(void* const* d_in, const int* in_sizes, int n_in,
                              void* d_out, int out_size, void* d_ws, size_t ws_size,
                              hipStream_t stream)
{
    const float* x    = (const float*)d_in[0];
    const float* wq   = (const float*)d_in[1];
    const float* bq   = (const float*)d_in[2];
    const float* wk   = (const float*)d_in[3];
    const float* bk   = (const float*)d_in[4];
    const float* wv   = (const float*)d_in[5];
    const float* bv   = (const float*)d_in[6];
    const float* cw   = (const float*)d_in[7];
    const float* cb   = (const float*)d_in[8];
    const float* m1w  = (const float*)d_in[9];
    const float* m2w  = (const float*)d_in[10];
    const float* bng  = (const float*)d_in[11];
    const float* bnb  = (const float*)d_in[12];
    const float* ln1g = (const float*)d_in[13];
    const float* ln1b = (const float*)d_in[14];
    const float* ln2g = (const float*)d_in[15];
    const float* ln2b = (const float*)d_in[16];

    float* outF = (float*)d_out;
    char*  wsb  = (char*)d_ws;
    if (ws_size < WS_NEED) return;

    ushort_t* QbG = (ushort_t*)(wsb + OFF_QB);
    ushort_t* KT  = (ushort_t*)(wsb + OFF_KT);
    ushort_t* VT  = (ushort_t*)(wsb + OFF_VT);
    float*    GP  = (float*)(wsb + OFF_GP);
    ushort_t* MT  = (ushort_t*)(wsb + OFF_MT);
    float*    SVP = (float*)(wsb + OFF_SVP);
    float*    SVC = (float*)(wsb + OFF_SVC);
    float*    RED = (float*)(wsb + OFF_RED);
    float*    ZSP = (float*)(wsb + OFF_ZSP);
    float*    L2  = (float*)(wsb + OFF_QB);   // alias: QbG+KT dead after attn/g
    float*    Z   = (float*)(wsb + OFF_GP);   // alias: GP dead after combine

    const dim3 b256(256);

    qkv_mfma<<<dim3(128, 3), b256, 0, stream>>>(x, wq, bq, wk, bk, wv, bv,
                                                QbG, KT, VT, RED, SVP);
    g_mfma<<<dim3(4, 2, 16), b256, 0, stream>>>(KT, VT, GP);
    combine_m<<<256, b256, 0, stream>>>(GP, cw, RED, SVP, cb, MT, SVC);
    attn_mfma<<<dim3(128, 2), b256, 0, stream>>>(QbG, MT, SVC, outF);
    ln_fuse<<<2048, b256, 0, stream>>>(x, outF, ln1g, ln1b, ln2g, ln2b, outF, L2);
    gemm_z64<<<128, b256, 0, stream>>>(L2, m1w, Z, ZSP);
    gemm_out32<<<dim3(256, 2), b256, 0, stream>>>(Z, m2w, ZSP, bng, bnb, outF);
}

// Round 8
// 135.663 us; speedup vs baseline: 21.0320x; 1.0699x over previous
//
#include <hip/hip_runtime.h>
#include <hip/hip_bf16.h>
#include <math.h>

// ---------------------------------------------------------------------------
// GraphBased_selfAttnLayer — collapsed attention path, 7 launches, all big
// GEMMs on MFMA, 256+ blocks per kernel for latency hiding.
//
//   G_v  = (S_{v-1} K)^T V            (MFMA, K-dim 8192, VT-layout + alignbit)
//   M_u  = scale * sum_v cw[u][v] G_v
//   attn = sum_u S_{u-1}(Q M_u) + cb*colsum(V)
//   h = x + LN1(attn); l2 = LN2(h); z = l2@m1w^T; BN; out = h + relu@m2w^T
//
// ws (bytes):
//   QbG bf16 [8194][256]   @ 0            (guard rows; aliased later by L2)
//   KT  bf16 [256][8192]   @  4,195,328   (aliased later by L2)
//   VT  bf16 [256][8200]   @  8,389,632   (guard cols 0/8193; VT[j][c]=V[c-1][j])
//   GP  f32 [48][256][256] @ 12,588,032   (aliased later by Z)
//   MT  bf16 [3][256][256] @ 25,170,944
//   SVP f32 [256][256]     @ 25,564,160
//   SVC f32 [256]          @ 25,826,304
//   RED f32 [512]          @ 25,827,328
//   ZSP f32 [256][256]     @ 25,829,376   (ends 26,091,520)
// ---------------------------------------------------------------------------

#define N_ 8192
#define D_ 256
#define H_ 128
#define EPSF 1e-5f

typedef unsigned short ushort_t;
typedef unsigned int uint_t;
typedef __attribute__((ext_vector_type(8))) short bf16x8;
typedef __attribute__((ext_vector_type(4))) short bf16x4;
typedef __attribute__((ext_vector_type(4))) float f32x4;

static const size_t OFF_QB  = 0;
static const size_t OFF_KT  = 4195328;
static const size_t OFF_VT  = 8389632;
static const size_t OFF_GP  = 12588032;
static const size_t OFF_MT  = 25170944;
static const size_t OFF_SVP = 25564160;
static const size_t OFF_SVC = 25826304;
static const size_t OFF_RED = 25827328;
static const size_t OFF_ZSP = 25829376;
static const size_t WS_NEED = 26091520;
// aliases: L2 f32 [8192][256] @0 (QbG+KT dead after attn/g);
//          Z  f32 [8192][128] @OFF_GP (GP dead after combine).

#define VT_S 8200   // VT row stride (elems); 8200*2 % 16 == 0

__device__ __forceinline__ ushort_t f2bf(float f) {
    __hip_bfloat16 h = __float2bfloat16(f);
    return reinterpret_cast<ushort_t&>(h);
}

__device__ __forceinline__ bf16x8 cvt8(float4 f0, float4 f1) {
    bf16x8 o;
    o[0] = (short)f2bf(f0.x); o[1] = (short)f2bf(f0.y);
    o[2] = (short)f2bf(f0.z); o[3] = (short)f2bf(f0.w);
    o[4] = (short)f2bf(f1.x); o[5] = (short)f2bf(f1.y);
    o[6] = (short)f2bf(f1.z); o[7] = (short)f2bf(f1.w);
    return o;
}

// ---------------------------------------------------------------------------
// qkv via MFMA, f32 inputs converted in-register. grid (256, 3).
// Block: 32 rows x 256 cols, 4 waves each 64 cols.
// Epilogues: Q -> QbG row-major (+1 row guard); K -> KT[d][t] (bf16x4);
// V -> VT[j][t+1] (split stores); sumsq (q,k) -> RED; colsum (v) -> SVP.
// ---------------------------------------------------------------------------
__global__ void __launch_bounds__(256)
qkv_mfma(const float* __restrict__ x,
         const float* __restrict__ wq, const float* __restrict__ bq,
         const float* __restrict__ wk, const float* __restrict__ bk,
         const float* __restrict__ wv, const float* __restrict__ bv,
         ushort_t* __restrict__ QbG, ushort_t* __restrict__ KT,
         ushort_t* __restrict__ VT,
         float* __restrict__ RED, float* __restrict__ SVP)
{
    __shared__ float lds4[4];
    const int tid = threadIdx.x, lane = tid & 63, wid = tid >> 6;
    const int sel = blockIdx.y;
    const int i0 = blockIdx.x * 32;
    const int jw = wid * 64;
    const int l15 = lane & 15, kg = lane >> 4;
    const float* W = (sel == 0) ? wq : ((sel == 1) ? wk : wv);
    const float* B = (sel == 0) ? bq : ((sel == 1) ? bk : bv);

    if (sel == 0 && blockIdx.x == 0) {
        QbG[tid] = 0; QbG[(size_t)8193 * 256 + tid] = 0;
        VT[(size_t)tid * VT_S] = 0; VT[(size_t)tid * VT_S + 8193] = 0;
    }

    f32x4 acc[2][4];
#pragma unroll
    for (int mi = 0; mi < 2; ++mi)
#pragma unroll
        for (int ni = 0; ni < 4; ++ni) acc[mi][ni] = 0.0f;

    for (int k0 = 0; k0 < 256; k0 += 32) {
        bf16x8 a[2], b[4];
#pragma unroll
        for (int mi = 0; mi < 2; ++mi) {
            const float* p = x + (size_t)(i0 + 16 * mi + l15) * 256 + k0 + 8 * kg;
            a[mi] = cvt8(*(const float4*)p, *(const float4*)(p + 4));
        }
#pragma unroll
        for (int ni = 0; ni < 4; ++ni) {
            const float* p = W + (size_t)(jw + 16 * ni + l15) * 256 + k0 + 8 * kg;
            b[ni] = cvt8(*(const float4*)p, *(const float4*)(p + 4));
        }
#pragma unroll
        for (int mi = 0; mi < 2; ++mi)
#pragma unroll
            for (int ni = 0; ni < 4; ++ni)
                acc[mi][ni] = __builtin_amdgcn_mfma_f32_16x16x32_bf16(a[mi], b[ni], acc[mi][ni], 0, 0, 0);
    }

    float ssq = 0.0f;
    float colp[4] = {0.0f, 0.0f, 0.0f, 0.0f};

    if (sel == 0) {
#pragma unroll
        for (int mi = 0; mi < 2; ++mi)
#pragma unroll
            for (int ni = 0; ni < 4; ++ni) {
                const int col = jw + 16 * ni + l15;
                const float bias = B[col];
#pragma unroll
                for (int r = 0; r < 4; ++r) {
                    const int row = i0 + 16 * mi + 4 * kg + r;
                    float val = acc[mi][ni][r] + bias;
                    QbG[(size_t)(row + 1) * 256 + col] = f2bf(val);
                    ssq = fmaf(val, val, ssq);
                }
            }
    } else if (sel == 1) {
#pragma unroll
        for (int mi = 0; mi < 2; ++mi)
#pragma unroll
            for (int ni = 0; ni < 4; ++ni) {
                const int col = jw + 16 * ni + l15;   // d
                const float bias = B[col];
                const int tb = i0 + 16 * mi + 4 * kg;
                bf16x4 pk;
#pragma unroll
                for (int r = 0; r < 4; ++r) {
                    float val = acc[mi][ni][r] + bias;
                    ssq = fmaf(val, val, ssq);
                    pk[r] = (short)f2bf(val);
                }
                *(bf16x4*)(KT + (size_t)col * 8192 + tb) = pk;
            }
    } else {
#pragma unroll
        for (int mi = 0; mi < 2; ++mi)
#pragma unroll
            for (int ni = 0; ni < 4; ++ni) {
                const int col = jw + 16 * ni + l15;   // j
                const float bias = B[col];
                const int tb = i0 + 16 * mi + 4 * kg;
                float v0 = acc[mi][ni][0] + bias, v1 = acc[mi][ni][1] + bias;
                float v2 = acc[mi][ni][2] + bias, v3 = acc[mi][ni][3] + bias;
                colp[ni] += v0 + v1 + v2 + v3;
                ushort_t* p = VT + (size_t)col * VT_S + tb + 1;
                p[0] = f2bf(v0);
                *(uint_t*)(p + 1) = (uint_t)f2bf(v1) | ((uint_t)f2bf(v2) << 16);
                p[3] = f2bf(v3);
            }
    }

    if (sel < 2) {
        float s = ssq;
#pragma unroll
        for (int o = 32; o > 0; o >>= 1) s += __shfl_down(s, o);
        if (lane == 0) lds4[wid] = s;
        __syncthreads();
        if (tid == 0)
            RED[sel * 256 + blockIdx.x] = lds4[0] + lds4[1] + lds4[2] + lds4[3];
    } else {
#pragma unroll
        for (int ni = 0; ni < 4; ++ni) {
            float v = colp[ni];
            v += __shfl_xor(v, 16);
            v += __shfl_xor(v, 32);
            if (kg == 0)
                SVP[(size_t)blockIdx.x * 256 + jw + 16 * ni + l15] = v;
        }
    }
}

// ---------------------------------------------------------------------------
// G_v[d][j] = sum_t K[t][d] * V[t+1-v][j].  grid (4, 4, 16) = 256 blocks.
// Block: 64d x 64j (4 waves each 64d x 16j), t-range 512 per ks.
// B-frags: 2 aligned dwordx4 loads give v=2 (r0) and v=0 (r2); v=1 built
// register-only: (r0>>16)|(r2<<16).
// ---------------------------------------------------------------------------
__global__ void __launch_bounds__(256)
g_mfma(const ushort_t* __restrict__ KT, const ushort_t* __restrict__ VT,
       float* __restrict__ GP)
{
    const int tid = threadIdx.x, lane = tid & 63, wid = tid >> 6;
    const int d0 = blockIdx.x * 64;
    const int jw = blockIdx.y * 64 + wid * 16;
    const int ks = blockIdx.z;
    const int l15 = lane & 15, kg = lane >> 4;

    f32x4 acc[3][4];
#pragma unroll
    for (int v = 0; v < 3; ++v)
#pragma unroll
        for (int mi = 0; mi < 4; ++mi) acc[v][mi] = 0.0f;

    for (int tt = 0; tt < 512; tt += 32) {
        const int t0 = ks * 512 + tt;
        bf16x8 a[4];
#pragma unroll
        for (int mi = 0; mi < 4; ++mi)
            a[mi] = *(const bf16x8*)(KT + (size_t)(d0 + 16 * mi + l15) * 8192 + t0 + 8 * kg);

        const ushort_t* vp = VT + (size_t)(jw + l15) * VT_S + t0 + 8 * kg;
        uint4 r0 = *(const uint4*)vp;          // cols +0..7 -> v=2
        uint4 r2 = *(const uint4*)(vp + 2);    // cols +2..9 -> v=0
        uint4 m1;
        m1.x = (r0.x >> 16) | (r2.x << 16);
        m1.y = (r0.y >> 16) | (r2.y << 16);
        m1.z = (r0.z >> 16) | (r2.z << 16);
        m1.w = (r0.w >> 16) | (r2.w << 16);    // cols +1..8 -> v=1
        bf16x8 b2 = __builtin_bit_cast(bf16x8, r0);
        bf16x8 b0 = __builtin_bit_cast(bf16x8, r2);
        bf16x8 b1 = __builtin_bit_cast(bf16x8, m1);
#pragma unroll
        for (int mi = 0; mi < 4; ++mi) {
            acc[0][mi] = __builtin_amdgcn_mfma_f32_16x16x32_bf16(a[mi], b0, acc[0][mi], 0, 0, 0);
            acc[1][mi] = __builtin_amdgcn_mfma_f32_16x16x32_bf16(a[mi], b1, acc[1][mi], 0, 0, 0);
            acc[2][mi] = __builtin_amdgcn_mfma_f32_16x16x32_bf16(a[mi], b2, acc[2][mi], 0, 0, 0);
        }
    }

#pragma unroll
    for (int v = 0; v < 3; ++v) {
        float* gp = GP + (size_t)(ks * 3 + v) * 65536;
#pragma unroll
        for (int mi = 0; mi < 4; ++mi)
#pragma unroll
            for (int r = 0; r < 4; ++r)
                gp[(size_t)(d0 + 16 * mi + 4 * kg + r) * 256 + (jw + l15)]
                    = acc[v][mi][r];
    }
}

// ---------------------------------------------------------------------------
// MT[u][j][d] = scale * sum_v cw[u][v] * sum_ks GP[ks*3+v][d][j]  (bf16).
// scale computed redundantly per block from RED; block 0 computes SVC.
// ---------------------------------------------------------------------------
__global__ void combine_m(const float* __restrict__ GP, const float* __restrict__ cw,
                          const float* __restrict__ RED, const float* __restrict__ SVP,
                          const float* __restrict__ cb,
                          ushort_t* __restrict__ MT, float* __restrict__ SVC)
{
    const int d = blockIdx.x, j = threadIdx.x;
    float g[3] = {0.0f, 0.0f, 0.0f};
    for (int ks = 0; ks < 16; ++ks)
#pragma unroll
        for (int v = 0; v < 3; ++v)
            g[v] += GP[(size_t)(ks * 3 + v) * 65536 + (size_t)d * 256 + j];

    float sq = 0.0f, sk = 0.0f;
    for (int i = 0; i < 256; ++i) { sq += RED[i]; sk += RED[256 + i]; }
    const float sc = rsqrtf(sq) * rsqrtf(sk);

#pragma unroll
    for (int u = 0; u < 3; ++u) {
        float m = sc * (cw[u * 3 + 0] * g[0] + cw[u * 3 + 1] * g[1] + cw[u * 3 + 2] * g[2]);
        MT[(size_t)u * 65536 + (size_t)j * 256 + d] = f2bf(m);
    }
    if (d == 0) {
        float s = 0.0f;
        for (int b = 0; b < 256; ++b) s += SVP[(size_t)b * 256 + j];
        SVC[j] = cb[0] * s;
    }
}

// ---------------------------------------------------------------------------
// attn[i][j] = sum_u sum_d Q[i+u-1][d] MT_u[j][d]  + SVC[j]
// grid (256, 2): 32-row x 128-col tiles, 4 waves each 32 cols.
// ---------------------------------------------------------------------------
__global__ void __launch_bounds__(256)
attn_mfma(const ushort_t* __restrict__ QbG, const ushort_t* __restrict__ MT,
          const float* __restrict__ SVC, float* __restrict__ attn)
{
    const int tid = threadIdx.x, lane = tid & 63, wid = tid >> 6;
    const int i0 = blockIdx.x * 32;
    const int jw = blockIdx.y * 128 + wid * 32;
    const int l15 = lane & 15, kg = lane >> 4;

    f32x4 acc[2][2];
#pragma unroll
    for (int mi = 0; mi < 2; ++mi) { acc[mi][0] = 0.0f; acc[mi][1] = 0.0f; }

    for (int k0 = 0; k0 < 256; k0 += 32) {
        bf16x8 a[3][2], b[3][2];
#pragma unroll
        for (int u = 0; u < 3; ++u)
#pragma unroll
            for (int mi = 0; mi < 2; ++mi)
                a[u][mi] = *(const bf16x8*)(QbG
                    + (size_t)(i0 + 16 * mi + l15 + u) * 256 + k0 + 8 * kg);
#pragma unroll
        for (int u = 0; u < 3; ++u)
#pragma unroll
            for (int ni = 0; ni < 2; ++ni)
                b[u][ni] = *(const bf16x8*)(MT + (size_t)u * 65536
                    + (size_t)(jw + 16 * ni + l15) * 256 + k0 + 8 * kg);
#pragma unroll
        for (int mi = 0; mi < 2; ++mi)
#pragma unroll
            for (int ni = 0; ni < 2; ++ni)
#pragma unroll
                for (int u = 0; u < 3; ++u)
                    acc[mi][ni] = __builtin_amdgcn_mfma_f32_16x16x32_bf16(
                        a[u][mi], b[u][ni], acc[mi][ni], 0, 0, 0);
    }

    float sv[2];
    sv[0] = SVC[jw + l15];
    sv[1] = SVC[jw + 16 + l15];
#pragma unroll
    for (int mi = 0; mi < 2; ++mi)
#pragma unroll
        for (int ni = 0; ni < 2; ++ni)
#pragma unroll
            for (int r = 0; r < 4; ++r)
                attn[(size_t)(i0 + 16 * mi + 4 * kg + r) * 256 + (jw + 16 * ni + l15)]
                    = acc[mi][ni][r] + sv[ni];
}

// ---------------------------------------------------------------------------
// h = x + LN1(attn) (in-place in d_out); l2 = LN2(h). Wave-per-row.
// ---------------------------------------------------------------------------
__device__ __forceinline__ float waveSum(float v)
{
#pragma unroll
    for (int o = 32; o > 0; o >>= 1) v += __shfl_xor(v, o);
    return v;
}

__global__ void ln_fuse(const float* __restrict__ x, const float* attn,
                        const float* __restrict__ ln1g, const float* __restrict__ ln1b,
                        const float* __restrict__ ln2g, const float* __restrict__ ln2b,
                        float* h, float* __restrict__ l2)
{
    const int lane = threadIdx.x & 63, wid = threadIdx.x >> 6;
    const size_t row = (size_t)blockIdx.x * 4 + wid;
    const size_t off = row * 256 + lane * 4;

    float4 a4 = *(const float4*)(attn + off);
    float m = waveSum(a4.x + a4.y + a4.z + a4.w) * (1.0f / D_);
    float4 d4 = make_float4(a4.x - m, a4.y - m, a4.z - m, a4.w - m);
    float var = waveSum(d4.x * d4.x + d4.y * d4.y + d4.z * d4.z + d4.w * d4.w) * (1.0f / D_);
    float rs = rsqrtf(var + EPSF);

    float4 x4 = *(const float4*)(x + off);
    float4 g4 = *(const float4*)(ln1g + lane * 4);
    float4 b4 = *(const float4*)(ln1b + lane * 4);
    float4 h4;
    h4.x = x4.x + d4.x * rs * g4.x + b4.x;
    h4.y = x4.y + d4.y * rs * g4.y + b4.y;
    h4.z = x4.z + d4.z * rs * g4.z + b4.z;
    h4.w = x4.w + d4.w * rs * g4.w + b4.w;
    *(float4*)(h + off) = h4;

    float m2 = waveSum(h4.x + h4.y + h4.z + h4.w) * (1.0f / D_);
    float4 e4 = make_float4(h4.x - m2, h4.y - m2, h4.z - m2, h4.w - m2);
    float v2 = waveSum(e4.x * e4.x + e4.y * e4.y + e4.z * e4.z + e4.w * e4.w) * (1.0f / D_);
    float rs2 = rsqrtf(v2 + EPSF);

    float4 g24 = *(const float4*)(ln2g + lane * 4);
    float4 b24 = *(const float4*)(ln2b + lane * 4);
    float4 o4;
    o4.x = e4.x * rs2 * g24.x + b24.x;
    o4.y = e4.y * rs2 * g24.y + b24.y;
    o4.z = e4.z * rs2 * g24.z + b24.z;
    o4.w = e4.w * rs2 * g24.w + b24.w;
    *(float4*)(l2 + off) = o4;
}

// ---------------------------------------------------------------------------
// z = l2 @ m1w^T via MFMA (f32->bf16 in-reg). grid 256: 32 rows x 128 cols,
// 4 waves each 32 cols. Epilogue: z store f32 + BN column partials -> ZSP.
// ---------------------------------------------------------------------------
__global__ void __launch_bounds__(256)
gemm_z_mfma(const float* __restrict__ L2, const float* __restrict__ W,
            float* __restrict__ Z, float* __restrict__ ZSP)
{
    const int tid = threadIdx.x, lane = tid & 63, wid = tid >> 6;
    const int i0 = blockIdx.x * 32;
    const int jw = wid * 32;
    const int l15 = lane & 15, kg = lane >> 4;

    f32x4 acc[2][2];
#pragma unroll
    for (int mi = 0; mi < 2; ++mi) { acc[mi][0] = 0.0f; acc[mi][1] = 0.0f; }

    for (int k0 = 0; k0 < 256; k0 += 32) {
        bf16x8 a[2], b[2];
#pragma unroll
        for (int mi = 0; mi < 2; ++mi) {
            const float* p = L2 + (size_t)(i0 + 16 * mi + l15) * 256 + k0 + 8 * kg;
            a[mi] = cvt8(*(const float4*)p, *(const float4*)(p + 4));
        }
#pragma unroll
        for (int ni = 0; ni < 2; ++ni) {
            const float* p = W + (size_t)(jw + 16 * ni + l15) * 256 + k0 + 8 * kg;
            b[ni] = cvt8(*(const float4*)p, *(const float4*)(p + 4));
        }
#pragma unroll
        for (int mi = 0; mi < 2; ++mi)
#pragma unroll
            for (int ni = 0; ni < 2; ++ni)
                acc[mi][ni] = __builtin_amdgcn_mfma_f32_16x16x32_bf16(a[mi], b[ni], acc[mi][ni], 0, 0, 0);
    }

    float s[2] = {0.0f, 0.0f}, q[2] = {0.0f, 0.0f};
#pragma unroll
    for (int mi = 0; mi < 2; ++mi)
#pragma unroll
        for (int ni = 0; ni < 2; ++ni) {
            const int col = jw + 16 * ni + l15;
#pragma unroll
            for (int r = 0; r < 4; ++r) {
                float zv = acc[mi][ni][r];
                Z[(size_t)(i0 + 16 * mi + 4 * kg + r) * 128 + col] = zv;
                s[ni] += zv;
                q[ni] = fmaf(zv, zv, q[ni]);
            }
        }
#pragma unroll
    for (int ni = 0; ni < 2; ++ni) {
        s[ni] += __shfl_xor(s[ni], 16); s[ni] += __shfl_xor(s[ni], 32);
        q[ni] += __shfl_xor(q[ni], 16); q[ni] += __shfl_xor(q[ni], 32);
        if (kg == 0) {
            ZSP[(size_t)blockIdx.x * 256 + jw + 16 * ni + l15] = s[ni];
            ZSP[(size_t)blockIdx.x * 256 + 128 + jw + 16 * ni + l15] = q[ni];
        }
    }
}

// ---------------------------------------------------------------------------
// out = h + relu(z*a+b) @ m2w^T via MFMA. grid 256: 32 rows x 256 cols,
// 4 waves each 64 cols. BN affine from ZSP in prologue (LDS).
// ---------------------------------------------------------------------------
__global__ void __launch_bounds__(256)
gemm_out_mfma(const float* __restrict__ Z, const float* __restrict__ W,
              const float* __restrict__ ZSP,
              const float* __restrict__ bng, const float* __restrict__ bnb,
              float* out)
{
    __shared__ float bnA[128], bnB[128];
    const int tid = threadIdx.x, lane = tid & 63, wid = tid >> 6;
    const int i0 = blockIdx.x * 32;
    const int jw = wid * 64;
    const int l15 = lane & 15, kg = lane >> 4;

    if (tid < 128) {
        float s = 0.0f, q = 0.0f;
        for (int b = 0; b < 256; ++b) {
            s += ZSP[(size_t)b * 256 + tid];
            q += ZSP[(size_t)b * 256 + 128 + tid];
        }
        float mu = s * (1.0f / N_);
        float var = q * (1.0f / N_) - mu * mu;
        float aa = rsqrtf(var + EPSF) * bng[tid];
        bnA[tid] = aa;
        bnB[tid] = bnb[tid] - mu * aa;
    }
    __syncthreads();

    f32x4 acc[2][4];
#pragma unroll
    for (int mi = 0; mi < 2; ++mi)
#pragma unroll
        for (int ni = 0; ni < 4; ++ni) acc[mi][ni] = 0.0f;

    for (int k0 = 0; k0 < 128; k0 += 32) {
        float ba[8], bb[8];
#pragma unroll
        for (int e = 0; e < 8; ++e) {
            ba[e] = bnA[k0 + 8 * kg + e];
            bb[e] = bnB[k0 + 8 * kg + e];
        }
        bf16x8 a[2], b[4];
#pragma unroll
        for (int mi = 0; mi < 2; ++mi) {
            const float* p = Z + (size_t)(i0 + 16 * mi + l15) * 128 + k0 + 8 * kg;
            float4 f0 = *(const float4*)p;
            float4 f1 = *(const float4*)(p + 4);
            float4 g0, g1;
            g0.x = fmaxf(fmaf(f0.x, ba[0], bb[0]), 0.0f);
            g0.y = fmaxf(fmaf(f0.y, ba[1], bb[1]), 0.0f);
            g0.z = fmaxf(fmaf(f0.z, ba[2], bb[2]), 0.0f);
            g0.w = fmaxf(fmaf(f0.w, ba[3], bb[3]), 0.0f);
            g1.x = fmaxf(fmaf(f1.x, ba[4], bb[4]), 0.0f);
            g1.y = fmaxf(fmaf(f1.y, ba[5], bb[5]), 0.0f);
            g1.z = fmaxf(fmaf(f1.z, ba[6], bb[6]), 0.0f);
            g1.w = fmaxf(fmaf(f1.w, ba[7], bb[7]), 0.0f);
            a[mi] = cvt8(g0, g1);
        }
#pragma unroll
        for (int ni = 0; ni < 4; ++ni) {
            const float* p = W + (size_t)(jw + 16 * ni + l15) * 128 + k0 + 8 * kg;
            b[ni] = cvt8(*(const float4*)p, *(const float4*)(p + 4));
        }
#pragma unroll
        for (int mi = 0; mi < 2; ++mi)
#pragma unroll
            for (int ni = 0; ni < 4; ++ni)
                acc[mi][ni] = __builtin_amdgcn_mfma_f32_16x16x32_bf16(a[mi], b[ni], acc[mi][ni], 0, 0, 0);
    }

#pragma unroll
    for (int mi = 0; mi < 2; ++mi)
#pragma unroll
        for (int ni = 0; ni < 4; ++ni)
#pragma unroll
            for (int r = 0; r < 4; ++r) {
                const size_t idx = (size_t)(i0 + 16 * mi + 4 * kg + r) * 256
                                 + (jw + 16 * ni + l15);
                out[idx] = out[idx] + acc[mi][ni][r];
            }
}

// ---------------------------------------------------------------------------
extern "C" void kernel_launch(void* const* d_in, const int* in_sizes, int n_in,
                              void* d_out, int out_size, void* d_ws, size_t ws_size,
                              hipStream_t stream)
{
    const float* x    = (const float*)d_in[0];
    const float* wq   = (const float*)d_in[1];
    const float* bq   = (const float*)d_in[2];
    const float* wk   = (const float*)d_in[3];
    const float* bk   = (const float*)d_in[4];
    const float* wv   = (const float*)d_in[5];
    const float* bv   = (const float*)d_in[6];
    const float* cw   = (const float*)d_in[7];
    const float* cb   = (const float*)d_in[8];
    const float* m1w  = (const float*)d_in[9];
    const float* m2w  = (const float*)d_in[10];
    const float* bng  = (const float*)d_in[11];
    const float* bnb  = (const float*)d_in[12];
    const float* ln1g = (const float*)d_in[13];
    const float* ln1b = (const float*)d_in[14];
    const float* ln2g = (const float*)d_in[15];
    const float* ln2b = (const float*)d_in[16];

    float* outF = (float*)d_out;
    char*  wsb  = (char*)d_ws;
    if (ws_size < WS_NEED) return;

    ushort_t* QbG = (ushort_t*)(wsb + OFF_QB);
    ushort_t* KT  = (ushort_t*)(wsb + OFF_KT);
    ushort_t* VT  = (ushort_t*)(wsb + OFF_VT);
    float*    GP  = (float*)(wsb + OFF_GP);
    ushort_t* MT  = (ushort_t*)(wsb + OFF_MT);
    float*    SVP = (float*)(wsb + OFF_SVP);
    float*    SVC = (float*)(wsb + OFF_SVC);
    float*    RED = (float*)(wsb + OFF_RED);
    float*    ZSP = (float*)(wsb + OFF_ZSP);
    float*    L2  = (float*)(wsb + OFF_QB);   // alias: QbG+KT dead after attn/g
    float*    Z   = (float*)(wsb + OFF_GP);   // alias: GP dead after combine

    const dim3 b256(256);

    qkv_mfma<<<dim3(256, 3), b256, 0, stream>>>(x, wq, bq, wk, bk, wv, bv,
                                                QbG, KT, VT, RED, SVP);
    g_mfma<<<dim3(4, 4, 16), b256, 0, stream>>>(KT, VT, GP);
    combine_m<<<256, b256, 0, stream>>>(GP, cw, RED, SVP, cb, MT, SVC);
    attn_mfma<<<dim3(256, 2), b256, 0, stream>>>(QbG, MT, SVC, outF);
    ln_fuse<<<2048, b256, 0, stream>>>(x, outF, ln1g, ln1b, ln2g, ln2b, outF, L2);
    gemm_z_mfma<<<256, b256, 0, stream>>>(L2, m1w, Z, ZSP);
    gemm_out_mfma<<<256, b256, 0, stream>>>(Z, m2w, ZSP, bng, bnb, outF);
}

// Round 9
// 105.137 us; speedup vs baseline: 27.1384x; 1.2903x over previous
//
#include <hip/hip_runtime.h>
#include <hip/hip_bf16.h>
#include <math.h>

// ---------------------------------------------------------------------------
// GraphBased_selfAttnLayer — collapsed attention path, 6 launches.
//
//   G_v  = (S_{v-1} K)^T V            (MFMA, K-dim 8192, VT-layout + alignbit)
//   M_u  = scale * sum_v cw[u][v] G_v
//   attn = sum_u S_{u-1}(Q M_u) + cb*colsum(V); h = x + LN1(attn); l2 = LN2(h)
//   z = l2@m1w^T; BN; out = h + relu@m2w^T
//
// Launches: qkv (LDS-staged MFMA) -> g -> combine -> attn+LN (fused) ->
//           z (+BN partials) -> out (+BN affine).
//
// ws (bytes):
//   QbG bf16 [8194][256]   @ 0            (guard rows; aliased later by L2)
//   KT  bf16 [256][8192]   @  4,195,328   (aliased later by L2)
//   VT  bf16 [256][8200]   @  8,389,632   (guard cols 0/8193; VT[j][c]=V[c-1][j])
//   GP  f32 [48][256][256] @ 12,588,032   (aliased later by Z)
//   MT  bf16 [3][256][256] @ 25,170,944
//   SVP f32 [256][256]     @ 25,564,160
//   SVC f32 [256]          @ 25,826,304
//   RED f32 [512]          @ 25,827,328
//   ZSP f32 [256][256]     @ 25,829,376   (ends 26,091,520)
// ---------------------------------------------------------------------------

#define N_ 8192
#define D_ 256
#define H_ 128
#define EPSF 1e-5f

typedef unsigned short ushort_t;
typedef unsigned int uint_t;
typedef __attribute__((ext_vector_type(8))) short bf16x8;
typedef __attribute__((ext_vector_type(4))) short bf16x4;
typedef __attribute__((ext_vector_type(4))) float f32x4;

static const size_t OFF_QB  = 0;
static const size_t OFF_KT  = 4195328;
static const size_t OFF_VT  = 8389632;
static const size_t OFF_GP  = 12588032;
static const size_t OFF_MT  = 25170944;
static const size_t OFF_SVP = 25564160;
static const size_t OFF_SVC = 25826304;
static const size_t OFF_RED = 25827328;
static const size_t OFF_ZSP = 25829376;
static const size_t WS_NEED = 26091520;
// aliases: L2 f32 [8192][256] @0 (QbG+KT dead after attn/g);
//          Z  f32 [8192][128] @OFF_GP (GP dead after combine).

#define VT_S 8200   // VT row stride (elems); 8200*2 % 16 == 0

__device__ __forceinline__ ushort_t f2bf(float f) {
    __hip_bfloat16 h = __float2bfloat16(f);
    return reinterpret_cast<ushort_t&>(h);
}

__device__ __forceinline__ bf16x8 cvt8(float4 f0, float4 f1) {
    bf16x8 o;
    o[0] = (short)f2bf(f0.x); o[1] = (short)f2bf(f0.y);
    o[2] = (short)f2bf(f0.z); o[3] = (short)f2bf(f0.w);
    o[4] = (short)f2bf(f1.x); o[5] = (short)f2bf(f1.y);
    o[6] = (short)f2bf(f1.z); o[7] = (short)f2bf(f1.w);
    return o;
}

__device__ __forceinline__ float waveSum(float v)
{
#pragma unroll
    for (int o = 32; o > 0; o >>= 1) v += __shfl_xor(v, o);
    return v;
}

// ---------------------------------------------------------------------------
// qkv via MFMA with LDS-staged operands. grid (256, 3), 256 thr.
// Block: 32 rows x 256 cols; 4 waves each 64 cols.
// XS: x tile bf16 [32][264] staged once (coalesced f32 loads, in-reg cvt).
// WS: W k-chunk bf16 [256][40] staged per k0 (coalesced).
// Fragments via ds_read_b128 (padding -> ~2-way conflicts, free).
// Epilogues: Q -> QbG (+1 row guard); K -> KT[d][t]; V -> VT[j][t+1];
// sumsq (q,k) -> RED; colsum (v) -> SVP.
// ---------------------------------------------------------------------------
__global__ void __launch_bounds__(256)
qkv_mfma(const float* __restrict__ x,
         const float* __restrict__ wq, const float* __restrict__ bq,
         const float* __restrict__ wk, const float* __restrict__ bk,
         const float* __restrict__ wv, const float* __restrict__ bv,
         ushort_t* __restrict__ QbG, ushort_t* __restrict__ KT,
         ushort_t* __restrict__ VT,
         float* __restrict__ RED, float* __restrict__ SVP)
{
    __shared__ ushort_t XS[32][264];
    __shared__ ushort_t WS[256][40];
    __shared__ float lds4[4];
    const int tid = threadIdx.x, lane = tid & 63, wid = tid >> 6;
    const int sel = blockIdx.y;
    const int i0 = blockIdx.x * 32;
    const int jw = wid * 64;
    const int l15 = lane & 15, kg = lane >> 4;
    const float* W = (sel == 0) ? wq : ((sel == 1) ? wk : wv);
    const float* B = (sel == 0) ? bq : ((sel == 1) ? bk : bv);

    if (sel == 0 && blockIdx.x == 0) {
        QbG[tid] = 0; QbG[(size_t)8193 * 256 + tid] = 0;
        VT[(size_t)tid * VT_S] = 0; VT[(size_t)tid * VT_S + 8193] = 0;
    }

    // stage x tile [32][256] -> XS (coalesced)
#pragma unroll
    for (int p = 0; p < 4; ++p) {
        int lin = p * 256 + tid;          // unit = 8 f32
        int row = lin >> 5;               // 0..31
        int c8  = (lin & 31) * 8;         // 0..248
        const float* xp = x + (size_t)(i0 + row) * 256 + c8;
        *(bf16x8*)(&XS[row][c8]) = cvt8(*(const float4*)xp, *(const float4*)(xp + 4));
    }

    f32x4 acc[2][4];
#pragma unroll
    for (int mi = 0; mi < 2; ++mi)
#pragma unroll
        for (int ni = 0; ni < 4; ++ni) acc[mi][ni] = 0.0f;

    for (int k0 = 0; k0 < 256; k0 += 32) {
        __syncthreads();   // prev-iter reads done (also covers XS staging)
        // stage W[:, k0:k0+32] -> WS (coalesced)
#pragma unroll
        for (int p = 0; p < 4; ++p) {
            int j  = p * 64 + (tid >> 2);
            int c8 = (tid & 3) * 8;
            const float* wp = W + (size_t)j * 256 + k0 + c8;
            *(bf16x8*)(&WS[j][c8]) = cvt8(*(const float4*)wp, *(const float4*)(wp + 4));
        }
        __syncthreads();

        bf16x8 a[2], b[4];
#pragma unroll
        for (int mi = 0; mi < 2; ++mi)
            a[mi] = *(const bf16x8*)(&XS[16 * mi + l15][k0 + 8 * kg]);
#pragma unroll
        for (int ni = 0; ni < 4; ++ni)
            b[ni] = *(const bf16x8*)(&WS[jw + 16 * ni + l15][8 * kg]);
#pragma unroll
        for (int mi = 0; mi < 2; ++mi)
#pragma unroll
            for (int ni = 0; ni < 4; ++ni)
                acc[mi][ni] = __builtin_amdgcn_mfma_f32_16x16x32_bf16(a[mi], b[ni], acc[mi][ni], 0, 0, 0);
    }

    float ssq = 0.0f;
    float colp[4] = {0.0f, 0.0f, 0.0f, 0.0f};

    if (sel == 0) {
#pragma unroll
        for (int mi = 0; mi < 2; ++mi)
#pragma unroll
            for (int ni = 0; ni < 4; ++ni) {
                const int col = jw + 16 * ni + l15;
                const float bias = B[col];
#pragma unroll
                for (int r = 0; r < 4; ++r) {
                    const int row = i0 + 16 * mi + 4 * kg + r;
                    float val = acc[mi][ni][r] + bias;
                    QbG[(size_t)(row + 1) * 256 + col] = f2bf(val);
                    ssq = fmaf(val, val, ssq);
                }
            }
    } else if (sel == 1) {
#pragma unroll
        for (int mi = 0; mi < 2; ++mi)
#pragma unroll
            for (int ni = 0; ni < 4; ++ni) {
                const int col = jw + 16 * ni + l15;   // d
                const float bias = B[col];
                const int tb = i0 + 16 * mi + 4 * kg;
                bf16x4 pk;
#pragma unroll
                for (int r = 0; r < 4; ++r) {
                    float val = acc[mi][ni][r] + bias;
                    ssq = fmaf(val, val, ssq);
                    pk[r] = (short)f2bf(val);
                }
                *(bf16x4*)(KT + (size_t)col * 8192 + tb) = pk;
            }
    } else {
#pragma unroll
        for (int mi = 0; mi < 2; ++mi)
#pragma unroll
            for (int ni = 0; ni < 4; ++ni) {
                const int col = jw + 16 * ni + l15;   // j
                const float bias = B[col];
                const int tb = i0 + 16 * mi + 4 * kg;
                float v0 = acc[mi][ni][0] + bias, v1 = acc[mi][ni][1] + bias;
                float v2 = acc[mi][ni][2] + bias, v3 = acc[mi][ni][3] + bias;
                colp[ni] += v0 + v1 + v2 + v3;
                ushort_t* p = VT + (size_t)col * VT_S + tb + 1;
                p[0] = f2bf(v0);
                *(uint_t*)(p + 1) = (uint_t)f2bf(v1) | ((uint_t)f2bf(v2) << 16);
                p[3] = f2bf(v3);
            }
    }

    if (sel < 2) {
        float s = ssq;
#pragma unroll
        for (int o = 32; o > 0; o >>= 1) s += __shfl_down(s, o);
        if (lane == 0) lds4[wid] = s;
        __syncthreads();
        if (tid == 0)
            RED[sel * 256 + blockIdx.x] = lds4[0] + lds4[1] + lds4[2] + lds4[3];
    } else {
#pragma unroll
        for (int ni = 0; ni < 4; ++ni) {
            float v = colp[ni];
            v += __shfl_xor(v, 16);
            v += __shfl_xor(v, 32);
            if (kg == 0)
                SVP[(size_t)blockIdx.x * 256 + jw + 16 * ni + l15] = v;
        }
    }
}

// ---------------------------------------------------------------------------
// G_v[d][j] = sum_t K[t][d] * V[t+1-v][j].  grid (4, 4, 16) = 256 blocks.
// ---------------------------------------------------------------------------
__global__ void __launch_bounds__(256)
g_mfma(const ushort_t* __restrict__ KT, const ushort_t* __restrict__ VT,
       float* __restrict__ GP)
{
    const int tid = threadIdx.x, lane = tid & 63, wid = tid >> 6;
    const int d0 = blockIdx.x * 64;
    const int jw = blockIdx.y * 64 + wid * 16;
    const int ks = blockIdx.z;
    const int l15 = lane & 15, kg = lane >> 4;

    f32x4 acc[3][4];
#pragma unroll
    for (int v = 0; v < 3; ++v)
#pragma unroll
        for (int mi = 0; mi < 4; ++mi) acc[v][mi] = 0.0f;

    for (int tt = 0; tt < 512; tt += 32) {
        const int t0 = ks * 512 + tt;
        bf16x8 a[4];
#pragma unroll
        for (int mi = 0; mi < 4; ++mi)
            a[mi] = *(const bf16x8*)(KT + (size_t)(d0 + 16 * mi + l15) * 8192 + t0 + 8 * kg);

        const ushort_t* vp = VT + (size_t)(jw + l15) * VT_S + t0 + 8 * kg;
        uint4 r0 = *(const uint4*)vp;          // cols +0..7 -> v=2
        uint4 r2 = *(const uint4*)(vp + 2);    // cols +2..9 -> v=0
        uint4 m1;
        m1.x = (r0.x >> 16) | (r2.x << 16);
        m1.y = (r0.y >> 16) | (r2.y << 16);
        m1.z = (r0.z >> 16) | (r2.z << 16);
        m1.w = (r0.w >> 16) | (r2.w << 16);    // cols +1..8 -> v=1
        bf16x8 b2 = __builtin_bit_cast(bf16x8, r0);
        bf16x8 b0 = __builtin_bit_cast(bf16x8, r2);
        bf16x8 b1 = __builtin_bit_cast(bf16x8, m1);
#pragma unroll
        for (int mi = 0; mi < 4; ++mi) {
            acc[0][mi] = __builtin_amdgcn_mfma_f32_16x16x32_bf16(a[mi], b0, acc[0][mi], 0, 0, 0);
            acc[1][mi] = __builtin_amdgcn_mfma_f32_16x16x32_bf16(a[mi], b1, acc[1][mi], 0, 0, 0);
            acc[2][mi] = __builtin_amdgcn_mfma_f32_16x16x32_bf16(a[mi], b2, acc[2][mi], 0, 0, 0);
        }
    }

#pragma unroll
    for (int v = 0; v < 3; ++v) {
        float* gp = GP + (size_t)(ks * 3 + v) * 65536;
#pragma unroll
        for (int mi = 0; mi < 4; ++mi)
#pragma unroll
            for (int r = 0; r < 4; ++r)
                gp[(size_t)(d0 + 16 * mi + 4 * kg + r) * 256 + (jw + l15)]
                    = acc[v][mi][r];
    }
}

// ---------------------------------------------------------------------------
// MT[u][j][d] = scale * sum_v cw[u][v] * sum_ks GP[ks*3+v][d][j]  (bf16).
// scale computed redundantly per block from RED; block 0 computes SVC.
// ---------------------------------------------------------------------------
__global__ void combine_m(const float* __restrict__ GP, const float* __restrict__ cw,
                          const float* __restrict__ RED, const float* __restrict__ SVP,
                          const float* __restrict__ cb,
                          ushort_t* __restrict__ MT, float* __restrict__ SVC)
{
    const int d = blockIdx.x, j = threadIdx.x;
    float g[3] = {0.0f, 0.0f, 0.0f};
    for (int ks = 0; ks < 16; ++ks)
#pragma unroll
        for (int v = 0; v < 3; ++v)
            g[v] += GP[(size_t)(ks * 3 + v) * 65536 + (size_t)d * 256 + j];

    float sq = 0.0f, sk = 0.0f;
    for (int i = 0; i < 256; ++i) { sq += RED[i]; sk += RED[256 + i]; }
    const float sc = rsqrtf(sq) * rsqrtf(sk);

#pragma unroll
    for (int u = 0; u < 3; ++u) {
        float m = sc * (cw[u * 3 + 0] * g[0] + cw[u * 3 + 1] * g[1] + cw[u * 3 + 2] * g[2]);
        MT[(size_t)u * 65536 + (size_t)j * 256 + d] = f2bf(m);
    }
    if (d == 0) {
        float s = 0.0f;
        for (int b = 0; b < 256; ++b) s += SVP[(size_t)b * 256 + j];
        SVC[j] = cb[0] * s;
    }
}

// ---------------------------------------------------------------------------
// attn + LN fused. grid 256: block = 32 full rows; 4 waves each 64 cols.
// attn[i][j] = sum_u sum_d Q[i+u-1][d] MT_u[j][d] + SVC[j]  -> LDS ->
// h = x + LN1(attn) -> d_out;  l2 = LN2(h) -> L2buf.
// ---------------------------------------------------------------------------
__global__ void __launch_bounds__(256)
attn_ln_mfma(const ushort_t* __restrict__ QbG, const ushort_t* __restrict__ MT,
             const float* __restrict__ SVC, const float* __restrict__ x,
             const float* __restrict__ ln1g, const float* __restrict__ ln1b,
             const float* __restrict__ ln2g, const float* __restrict__ ln2b,
             float* __restrict__ h, float* __restrict__ l2)
{
    __shared__ float OUT[32][258];
    const int tid = threadIdx.x, lane = tid & 63, wid = tid >> 6;
    const int i0 = blockIdx.x * 32;
    const int jw = wid * 64;
    const int l15 = lane & 15, kg = lane >> 4;

    f32x4 acc[2][4];
#pragma unroll
    for (int mi = 0; mi < 2; ++mi)
#pragma unroll
        for (int ni = 0; ni < 4; ++ni) acc[mi][ni] = 0.0f;

    for (int k0 = 0; k0 < 256; k0 += 32) {
        bf16x8 a[3][2], b[3][4];
#pragma unroll
        for (int u = 0; u < 3; ++u)
#pragma unroll
            for (int mi = 0; mi < 2; ++mi)
                a[u][mi] = *(const bf16x8*)(QbG
                    + (size_t)(i0 + 16 * mi + l15 + u) * 256 + k0 + 8 * kg);
#pragma unroll
        for (int u = 0; u < 3; ++u)
#pragma unroll
            for (int ni = 0; ni < 4; ++ni)
                b[u][ni] = *(const bf16x8*)(MT + (size_t)u * 65536
                    + (size_t)(jw + 16 * ni + l15) * 256 + k0 + 8 * kg);
#pragma unroll
        for (int mi = 0; mi < 2; ++mi)
#pragma unroll
            for (int ni = 0; ni < 4; ++ni)
#pragma unroll
                for (int u = 0; u < 3; ++u)
                    acc[mi][ni] = __builtin_amdgcn_mfma_f32_16x16x32_bf16(
                        a[u][mi], b[u][ni], acc[mi][ni], 0, 0, 0);
    }

#pragma unroll
    for (int mi = 0; mi < 2; ++mi)
#pragma unroll
        for (int ni = 0; ni < 4; ++ni) {
            const int col = jw + 16 * ni + l15;
            const float sv = SVC[col];
#pragma unroll
            for (int r = 0; r < 4; ++r)
                OUT[16 * mi + 4 * kg + r][col] = acc[mi][ni][r] + sv;
        }
    __syncthreads();

    // LN over this block's 32 rows: wave handles rows wid*8 .. wid*8+8
    const float4 g14 = *(const float4*)(ln1g + lane * 4);
    const float4 b14 = *(const float4*)(ln1b + lane * 4);
    const float4 g24 = *(const float4*)(ln2g + lane * 4);
    const float4 b24 = *(const float4*)(ln2b + lane * 4);
#pragma unroll
    for (int rr = 0; rr < 8; ++rr) {
        const int row_l = wid * 8 + rr;
        const size_t off = (size_t)(i0 + row_l) * 256 + lane * 4;

        float4 a4 = *(const float4*)&OUT[row_l][lane * 4];
        float m = waveSum(a4.x + a4.y + a4.z + a4.w) * (1.0f / D_);
        float4 d4 = make_float4(a4.x - m, a4.y - m, a4.z - m, a4.w - m);
        float var = waveSum(d4.x * d4.x + d4.y * d4.y + d4.z * d4.z + d4.w * d4.w) * (1.0f / D_);
        float rs = rsqrtf(var + EPSF);

        float4 x4 = *(const float4*)(x + off);
        float4 h4;
        h4.x = x4.x + d4.x * rs * g14.x + b14.x;
        h4.y = x4.y + d4.y * rs * g14.y + b14.y;
        h4.z = x4.z + d4.z * rs * g14.z + b14.z;
        h4.w = x4.w + d4.w * rs * g14.w + b14.w;
        *(float4*)(h + off) = h4;

        float m2 = waveSum(h4.x + h4.y + h4.z + h4.w) * (1.0f / D_);
        float4 e4 = make_float4(h4.x - m2, h4.y - m2, h4.z - m2, h4.w - m2);
        float v2 = waveSum(e4.x * e4.x + e4.y * e4.y + e4.z * e4.z + e4.w * e4.w) * (1.0f / D_);
        float rs2 = rsqrtf(v2 + EPSF);

        float4 o4;
        o4.x = e4.x * rs2 * g24.x + b24.x;
        o4.y = e4.y * rs2 * g24.y + b24.y;
        o4.z = e4.z * rs2 * g24.z + b24.z;
        o4.w = e4.w * rs2 * g24.w + b24.w;
        *(float4*)(l2 + off) = o4;
    }
}

// ---------------------------------------------------------------------------
// z = l2 @ m1w^T via MFMA (f32->bf16 in-reg). grid 256: 32 rows x 128 cols,
// 4 waves each 32 cols. Epilogue: z store f32 + BN column partials -> ZSP.
// ---------------------------------------------------------------------------
__global__ void __launch_bounds__(256)
gemm_z_mfma(const float* __restrict__ L2, const float* __restrict__ W,
            float* __restrict__ Z, float* __restrict__ ZSP)
{
    const int tid = threadIdx.x, lane = tid & 63, wid = tid >> 6;
    const int i0 = blockIdx.x * 32;
    const int jw = wid * 32;
    const int l15 = lane & 15, kg = lane >> 4;

    f32x4 acc[2][2];
#pragma unroll
    for (int mi = 0; mi < 2; ++mi) { acc[mi][0] = 0.0f; acc[mi][1] = 0.0f; }

    for (int k0 = 0; k0 < 256; k0 += 32) {
        bf16x8 a[2], b[2];
#pragma unroll
        for (int mi = 0; mi < 2; ++mi) {
            const float* p = L2 + (size_t)(i0 + 16 * mi + l15) * 256 + k0 + 8 * kg;
            a[mi] = cvt8(*(const float4*)p, *(const float4*)(p + 4));
        }
#pragma unroll
        for (int ni = 0; ni < 2; ++ni) {
            const float* p = W + (size_t)(jw + 16 * ni + l15) * 256 + k0 + 8 * kg;
            b[ni] = cvt8(*(const float4*)p, *(const float4*)(p + 4));
        }
#pragma unroll
        for (int mi = 0; mi < 2; ++mi)
#pragma unroll
            for (int ni = 0; ni < 2; ++ni)
                acc[mi][ni] = __builtin_amdgcn_mfma_f32_16x16x32_bf16(a[mi], b[ni], acc[mi][ni], 0, 0, 0);
    }

    float s[2] = {0.0f, 0.0f}, q[2] = {0.0f, 0.0f};
#pragma unroll
    for (int mi = 0; mi < 2; ++mi)
#pragma unroll
        for (int ni = 0; ni < 2; ++ni) {
            const int col = jw + 16 * ni + l15;
#pragma unroll
            for (int r = 0; r < 4; ++r) {
                float zv = acc[mi][ni][r];
                Z[(size_t)(i0 + 16 * mi + 4 * kg + r) * 128 + col] = zv;
                s[ni] += zv;
                q[ni] = fmaf(zv, zv, q[ni]);
            }
        }
#pragma unroll
    for (int ni = 0; ni < 2; ++ni) {
        s[ni] += __shfl_xor(s[ni], 16); s[ni] += __shfl_xor(s[ni], 32);
        q[ni] += __shfl_xor(q[ni], 16); q[ni] += __shfl_xor(q[ni], 32);
        if (kg == 0) {
            ZSP[(size_t)blockIdx.x * 256 + jw + 16 * ni + l15] = s[ni];
            ZSP[(size_t)blockIdx.x * 256 + 128 + jw + 16 * ni + l15] = q[ni];
        }
    }
}

// ---------------------------------------------------------------------------
// out = h + relu(z*a+b) @ m2w^T via MFMA. grid 256: 32 rows x 256 cols,
// 4 waves each 64 cols. BN affine from ZSP in prologue (LDS).
// ---------------------------------------------------------------------------
__global__ void __launch_bounds__(256)
gemm_out_mfma(const float* __restrict__ Z, const float* __restrict__ W,
              const float* __restrict__ ZSP,
              const float* __restrict__ bng, const float* __restrict__ bnb,
              float* out)
{
    __shared__ float bnA[128], bnB[128];
    const int tid = threadIdx.x, lane = tid & 63, wid = tid >> 6;
    const int i0 = blockIdx.x * 32;
    const int jw = wid * 64;
    const int l15 = lane & 15, kg = lane >> 4;

    if (tid < 128) {
        float s = 0.0f, q = 0.0f;
        for (int b = 0; b < 256; ++b) {
            s += ZSP[(size_t)b * 256 + tid];
            q += ZSP[(size_t)b * 256 + 128 + tid];
        }
        float mu = s * (1.0f / N_);
        float var = q * (1.0f / N_) - mu * mu;
        float aa = rsqrtf(var + EPSF) * bng[tid];
        bnA[tid] = aa;
        bnB[tid] = bnb[tid] - mu * aa;
    }
    __syncthreads();

    f32x4 acc[2][4];
#pragma unroll
    for (int mi = 0; mi < 2; ++mi)
#pragma unroll
        for (int ni = 0; ni < 4; ++ni) acc[mi][ni] = 0.0f;

    for (int k0 = 0; k0 < 128; k0 += 32) {
        float ba[8], bb[8];
#pragma unroll
        for (int e = 0; e < 8; ++e) {
            ba[e] = bnA[k0 + 8 * kg + e];
            bb[e] = bnB[k0 + 8 * kg + e];
        }
        bf16x8 a[2], b[4];
#pragma unroll
        for (int mi = 0; mi < 2; ++mi) {
            const float* p = Z + (size_t)(i0 + 16 * mi + l15) * 128 + k0 + 8 * kg;
            float4 f0 = *(const float4*)p;
            float4 f1 = *(const float4*)(p + 4);
            float4 g0, g1;
            g0.x = fmaxf(fmaf(f0.x, ba[0], bb[0]), 0.0f);
            g0.y = fmaxf(fmaf(f0.y, ba[1], bb[1]), 0.0f);
            g0.z = fmaxf(fmaf(f0.z, ba[2], bb[2]), 0.0f);
            g0.w = fmaxf(fmaf(f0.w, ba[3], bb[3]), 0.0f);
            g1.x = fmaxf(fmaf(f1.x, ba[4], bb[4]), 0.0f);
            g1.y = fmaxf(fmaf(f1.y, ba[5], bb[5]), 0.0f);
            g1.z = fmaxf(fmaf(f1.z, ba[6], bb[6]), 0.0f);
            g1.w = fmaxf(fmaf(f1.w, ba[7], bb[7]), 0.0f);
            a[mi] = cvt8(g0, g1);
        }
#pragma unroll
        for (int ni = 0; ni < 4; ++ni) {
            const float* p = W + (size_t)(jw + 16 * ni + l15) * 128 + k0 + 8 * kg;
            b[ni] = cvt8(*(const float4*)p, *(const float4*)(p + 4));
        }
#pragma unroll
        for (int mi = 0; mi < 2; ++mi)
#pragma unroll
            for (int ni = 0; ni < 4; ++ni)
                acc[mi][ni] = __builtin_amdgcn_mfma_f32_16x16x32_bf16(a[mi], b[ni], acc[mi][ni], 0, 0, 0);
    }

#pragma unroll
    for (int mi = 0; mi < 2; ++mi)
#pragma unroll
        for (int ni = 0; ni < 4; ++ni)
#pragma unroll
            for (int r = 0; r < 4; ++r) {
                const size_t idx = (size_t)(i0 + 16 * mi + 4 * kg + r) * 256
                                 + (jw + 16 * ni + l15);
                out[idx] = out[idx] + acc[mi][ni][r];
            }
}

// ---------------------------------------------------------------------------
extern "C" void kernel_launch(void* const* d_in, const int* in_sizes, int n_in,
                              void* d_out, int out_size, void* d_ws, size_t ws_size,
                              hipStream_t stream)
{
    const float* x    = (const float*)d_in[0];
    const float* wq   = (const float*)d_in[1];
    const float* bq   = (const float*)d_in[2];
    const float* wk   = (const float*)d_in[3];
    const float* bk   = (const float*)d_in[4];
    const float* wv   = (const float*)d_in[5];
    const float* bv   = (const float*)d_in[6];
    const float* cw   = (const float*)d_in[7];
    const float* cb   = (const float*)d_in[8];
    const float* m1w  = (const float*)d_in[9];
    const float* m2w  = (const float*)d_in[10];
    const float* bng  = (const float*)d_in[11];
    const float* bnb  = (const float*)d_in[12];
    const float* ln1g = (const float*)d_in[13];
    const float* ln1b = (const float*)d_in[14];
    const float* ln2g = (const float*)d_in[15];
    const float* ln2b = (const float*)d_in[16];

    float* outF = (float*)d_out;
    char*  wsb  = (char*)d_ws;
    if (ws_size < WS_NEED) return;

    ushort_t* QbG = (ushort_t*)(wsb + OFF_QB);
    ushort_t* KT  = (ushort_t*)(wsb + OFF_KT);
    ushort_t* VT  = (ushort_t*)(wsb + OFF_VT);
    float*    GP  = (float*)(wsb + OFF_GP);
    ushort_t* MT  = (ushort_t*)(wsb + OFF_MT);
    float*    SVP = (float*)(wsb + OFF_SVP);
    float*    SVC = (float*)(wsb + OFF_SVC);
    float*    RED = (float*)(wsb + OFF_RED);
    float*    ZSP = (float*)(wsb + OFF_ZSP);
    float*    L2  = (float*)(wsb + OFF_QB);   // alias: QbG+KT dead after attn/g
    float*    Z   = (float*)(wsb + OFF_GP);   // alias: GP dead after combine

    const dim3 b256(256);

    qkv_mfma<<<dim3(256, 3), b256, 0, stream>>>(x, wq, bq, wk, bk, wv, bv,
                                                QbG, KT, VT, RED, SVP);
    g_mfma<<<dim3(4, 4, 16), b256, 0, stream>>>(KT, VT, GP);
    combine_m<<<256, b256, 0, stream>>>(GP, cw, RED, SVP, cb, MT, SVC);
    attn_ln_mfma<<<256, b256, 0, stream>>>(QbG, MT, SVC, x,
                                           ln1g, ln1b, ln2g, ln2b, outF, L2);
    gemm_z_mfma<<<256, b256, 0, stream>>>(L2, m1w, Z, ZSP);
    gemm_out_mfma<<<256, b256, 0, stream>>>(Z, m2w, ZSP, bng, bnb, outF);
}